// Round 1
// baseline (26736.765 us; speedup 1.0000x reference)
//
#include <hip/hip_runtime.h>
#include <math.h>

#define DM    1024
#define NH    16
#define DKH   64
#define NL    4
#define DFFN  4096
#define BB    4
#define TT    1024
#define NSTEP 24
#define BT    (BB*TT)      // 4096 encoder rows
#define MD    (BB*NSTEP)   // 96 decoder rows (fixed padding; only first n valid per step)
#define CSPLIT 8
#define CKEYS  (TT/CSPLIT) // 128 keys per cross-attn split

// ---------------- positional encoding table ----------------
__global__ void pe_kernel(float* __restrict__ pe) {
  const int pos = blockIdx.x;
  for (int ii = threadIdx.x; ii < DM/2; ii += 256) {
    float ang = (float)pos * expf((float)(2*ii) * (-9.210340371976184f / (float)DM));
    pe[(size_t)pos*DM + 2*ii]     = sinf(ang);
    pe[(size_t)pos*DM + 2*ii + 1] = cosf(ang);
  }
}

__global__ void zero_kernel(float* __restrict__ p, int n) {
  int i = blockIdx.x*256 + threadIdx.x;
  if (i < n) p[i] = 0.f;
}

// h[row] += pe[row % TT]
__global__ __launch_bounds__(256) void add_pe_enc(float* __restrict__ h,
                                                  const float* __restrict__ pe) {
  const int row = blockIdx.x;
  const int t = row & (TT-1);
  const int d = threadIdx.x*4;
  float4 a = *(const float4*)(h + (size_t)row*DM + d);
  const float4 p = *(const float4*)(pe + (size_t)t*DM + d);
  a.x += p.x; a.y += p.y; a.z += p.z; a.w += p.w;
  *(float4*)(h + (size_t)row*DM + d) = a;
}

// dbuf[b,i] = tok[b,i] + pe[i]
__global__ __launch_bounds__(256) void dec_prep(float* __restrict__ dbuf,
        const float* __restrict__ tok, const float* __restrict__ pe) {
  const int row = blockIdx.x;           // b*NSTEP + i
  const int i = row % NSTEP;
  const int d = threadIdx.x*4;
  const float4 a = *(const float4*)(tok + (size_t)row*DM + d);
  const float4 p = *(const float4*)(pe + (size_t)i*DM + d);
  float4 o; o.x=a.x+p.x; o.y=a.y+p.y; o.z=a.z+p.z; o.w=a.w+p.w;
  *(float4*)(dbuf + (size_t)row*DM + d) = o;
}

// ---------------- big f32 GEMM: C[M,N] = A[M,K] @ W[N,K]^T + bias ----------------
// 128x128 tile, 256 threads, 8x8 per thread. M,N multiples of 128; K multiple of 16.
template<int ACT>
__global__ __launch_bounds__(256)
void gemm_nt(const float* __restrict__ A, const float* __restrict__ Wt,
             const float* __restrict__ bias, float* __restrict__ C,
             int M, int N, int K)
{
  __shared__ float As[16][132];
  __shared__ float Ws[16][132];
  const int tid = threadIdx.x;
  const int m0 = blockIdx.x*128, n0 = blockIdx.y*128;
  const int tx = tid & 15, ty = tid >> 4;
  float acc[8][8];
  #pragma unroll
  for (int i=0;i<8;i++)
    #pragma unroll
    for (int j=0;j<8;j++) acc[i][j]=0.f;

  for (int k0 = 0; k0 < K; k0 += 16) {
    __syncthreads();
    #pragma unroll
    for (int t=0;t<2;t++) {
      const int fi = tid + t*256;           // 0..511 float4 slots
      const int row = fi >> 2, kq = fi & 3; // 128 rows x 4 quads
      const float4 va = *(const float4*)(A  + (size_t)(m0+row)*K + k0 + kq*4);
      As[kq*4+0][row]=va.x; As[kq*4+1][row]=va.y; As[kq*4+2][row]=va.z; As[kq*4+3][row]=va.w;
      const float4 vw = *(const float4*)(Wt + (size_t)(n0+row)*K + k0 + kq*4);
      Ws[kq*4+0][row]=vw.x; Ws[kq*4+1][row]=vw.y; Ws[kq*4+2][row]=vw.z; Ws[kq*4+3][row]=vw.w;
    }
    __syncthreads();
    #pragma unroll
    for (int kk=0;kk<16;kk++) {
      float a[8], b[8];
      #pragma unroll
      for (int i=0;i<8;i++) a[i] = As[kk][ty*8+i];   // contiguous -> b128 pair
      #pragma unroll
      for (int j=0;j<8;j++) b[j] = Ws[kk][tx + j*16]; // stride-16 -> conflict-free b32
      #pragma unroll
      for (int i=0;i<8;i++)
        #pragma unroll
        for (int j=0;j<8;j++) acc[i][j] = fmaf(a[i], b[j], acc[i][j]);
    }
  }
  #pragma unroll
  for (int j=0;j<8;j++) {
    const int col = n0 + tx + j*16;
    const float bv = bias[col];
    #pragma unroll
    for (int i=0;i<8;i++) {
      float v = acc[i][j] + bv;
      if (ACT==1) v = fmaxf(v, 0.f);
      C[(size_t)(m0+ty*8+i)*N + col] = v;
    }
  }
}

// ---------------- skinny GEMM (M=96) with K-split partials ----------------
// grid (N/64, KS, NG); part layout [NG][KS][96][N]
__global__ __launch_bounds__(256)
void gemm_skinny(const float* __restrict__ A,
                 const float* __restrict__ W0, const float* __restrict__ W1,
                 const float* __restrict__ W2,
                 float* __restrict__ part, int N, int K, int KS)
{
  const float* Wt = (blockIdx.z==0) ? W0 : (blockIdx.z==1 ? W1 : W2);
  float* P = part + ((size_t)blockIdx.z*KS + blockIdx.y)*(size_t)MD*N;
  const int KK = K / KS;
  const int kbase = blockIdx.y * KK;
  const int n0 = blockIdx.x * 64;
  __shared__ float As[MD][68];
  __shared__ float Ws[64][68];
  const int tid = threadIdx.x;
  const int cg = tid & 15, rg = tid >> 4;  // cols cg+j*16, rows rg*6+i
  float acc[6][4];
  #pragma unroll
  for (int i=0;i<6;i++)
    #pragma unroll
    for (int j=0;j<4;j++) acc[i][j]=0.f;

  for (int kc=0; kc<KK; kc+=64) {
    const int k0 = kbase + kc;
    __syncthreads();
    #pragma unroll
    for (int t=0;t<6;t++) {     // A: 96x64 = 1536 float4
      const int fi = tid + t*256; const int row = fi>>4, kq = fi&15;
      *(float4*)&As[row][kq*4] = *(const float4*)(A + (size_t)row*K + k0 + kq*4);
    }
    #pragma unroll
    for (int t=0;t<4;t++) {     // W: 64x64 = 1024 float4
      const int fi = tid + t*256; const int row = fi>>4, kq = fi&15;
      *(float4*)&Ws[row][kq*4] = *(const float4*)(Wt + (size_t)(n0+row)*K + k0 + kq*4);
    }
    __syncthreads();
    #pragma unroll 4
    for (int kk=0;kk<64;kk++) {
      float w[4], a[6];
      #pragma unroll
      for (int j=0;j<4;j++) w[j] = Ws[cg + j*16][kk];
      #pragma unroll
      for (int i=0;i<6;i++) a[i] = As[rg*6+i][kk];
      #pragma unroll
      for (int i=0;i<6;i++)
        #pragma unroll
        for (int j=0;j<4;j++) acc[i][j] = fmaf(a[i], w[j], acc[i][j]);
    }
  }
  #pragma unroll
  for (int i=0;i<6;i++)
    #pragma unroll
    for (int j=0;j<4;j++)
      P[(size_t)(rg*6+i)*N + n0 + cg + j*16] = acc[i][j];
}

template<int ACT>
__global__ __launch_bounds__(256)
void reduce_part(const float* __restrict__ part,
                 const float* __restrict__ b0, const float* __restrict__ b1,
                 const float* __restrict__ b2,
                 float* __restrict__ o0, float* __restrict__ o1, float* __restrict__ o2,
                 int N, int KS)
{
  const int idx = blockIdx.x*256 + threadIdx.x;  // < MD*N
  const float* P = part + (size_t)blockIdx.y*KS*(size_t)MD*N;
  const float* bias = (blockIdx.y==0)?b0:(blockIdx.y==1?b1:b2);
  float* out = (blockIdx.y==0)?o0:(blockIdx.y==1?o1:o2);
  float s = 0.f;
  for (int ks=0; ks<KS; ks++) s += P[(size_t)ks*MD*N + idx];
  s += bias[idx & (N-1)];
  if (ACT==1) s = fmaxf(s, 0.f);
  out[idx] = s;
}

// ---------------- encoder self-attention (flash, thread-per-q-row) ----------------
__global__ __launch_bounds__(256)
void attn_enc(const float* __restrict__ Qg, const float* __restrict__ Kg,
              const float* __restrict__ Vg, float* __restrict__ Og)
{
  const int bh = blockIdx.y;
  const int b = bh >> 4, hh = bh & 15;
  const int row = blockIdx.x*256 + threadIdx.x;
  const size_t base = ((size_t)b*TT)*DM + hh*DKH;
  float q[64];
  {
    const float* qp = Qg + base + (size_t)row*DM;
    #pragma unroll
    for (int d4=0; d4<16; d4++){
      const float4 v = *(const float4*)(qp + d4*4);
      q[d4*4+0]=v.x; q[d4*4+1]=v.y; q[d4*4+2]=v.z; q[d4*4+3]=v.w;
    }
  }
  float o[64];
  #pragma unroll
  for (int d=0;d<64;d++) o[d]=0.f;
  float m = -INFINITY, l = 0.f;
  __shared__ float Ks[64][68];
  __shared__ float Vs[64][68];
  for (int kt=0; kt<TT; kt+=64) {
    __syncthreads();
    #pragma unroll
    for (int t=0;t<4;t++){
      const int fi = threadIdx.x + t*256;
      const int j = fi>>4, dq = fi&15;
      *(float4*)&Ks[j][dq*4] = *(const float4*)(Kg + base + (size_t)(kt+j)*DM + dq*4);
      *(float4*)&Vs[j][dq*4] = *(const float4*)(Vg + base + (size_t)(kt+j)*DM + dq*4);
    }
    __syncthreads();
    for (int j=0;j<64;j++){
      float s0=0.f,s1=0.f,s2=0.f,s3=0.f;
      #pragma unroll
      for (int d=0; d<64; d+=4){
        s0 = fmaf(q[d+0], Ks[j][d+0], s0);
        s1 = fmaf(q[d+1], Ks[j][d+1], s1);
        s2 = fmaf(q[d+2], Ks[j][d+2], s2);
        s3 = fmaf(q[d+3], Ks[j][d+3], s3);
      }
      const float s = ((s0+s1)+(s2+s3)) * 0.125f;
      if (s > m) {                       // defer-max rescale (rare after warmup)
        const float f = __expf(m - s);   // m=-inf first hit -> f=0
        l *= f;
        #pragma unroll
        for (int d=0;d<64;d++) o[d] *= f;
        m = s;
      }
      const float p = __expf(s - m);
      l += p;
      #pragma unroll
      for (int d=0;d<64;d++) o[d] = fmaf(p, Vs[j][d], o[d]);
    }
  }
  const float inv = 1.f / l;
  float* op = Og + base + (size_t)row*DM;
  #pragma unroll
  for (int d4=0; d4<16; d4++){
    float4 v;
    v.x=o[d4*4+0]*inv; v.y=o[d4*4+1]*inv; v.z=o[d4*4+2]*inv; v.w=o[d4*4+3]*inv;
    *(float4*)(op + d4*4) = v;
  }
}

// ---------------- decoder self-attention (tiny, one block per (b,h)) ----------------
__global__ __launch_bounds__(256)
void attn_dec_self(const float* __restrict__ Qg, const float* __restrict__ Kg,
                   const float* __restrict__ Vg, float* __restrict__ Og, int n)
{
  const int b = blockIdx.x >> 4, hh = blockIdx.x & 15;
  const size_t base = ((size_t)b*NSTEP)*DM + hh*DKH;
  __shared__ float Qs[NSTEP][68], Ks[NSTEP][68], Vs[NSTEP][68];
  __shared__ float P[NSTEP][28];
  const int tid = threadIdx.x;
  for (int t = tid; t < 3*NSTEP*16; t += 256) {
    const int tensor = t / (NSTEP*16);
    const int fi = t - tensor*(NSTEP*16);
    const int row = fi >> 4, dq = fi & 15;
    const float* src = (tensor==0?Qg:(tensor==1?Kg:Vg)) + base + (size_t)row*DM + dq*4;
    float (*dst)[68] = (tensor==0?Qs:(tensor==1?Ks:Vs));
    *(float4*)&dst[row][dq*4] = *(const float4*)src;
  }
  __syncthreads();
  for (int idx = tid; idx < NSTEP*n; idx += 256) {
    const int i = idx / n, j = idx - i*n;
    float s0=0.f,s1=0.f,s2=0.f,s3=0.f;
    #pragma unroll
    for (int d=0; d<64; d+=4){
      s0 = fmaf(Qs[i][d+0], Ks[j][d+0], s0);
      s1 = fmaf(Qs[i][d+1], Ks[j][d+1], s1);
      s2 = fmaf(Qs[i][d+2], Ks[j][d+2], s2);
      s3 = fmaf(Qs[i][d+3], Ks[j][d+3], s3);
    }
    P[i][j] = ((s0+s1)+(s2+s3))*0.125f;
  }
  __syncthreads();
  if (tid < NSTEP) {
    float mm = -INFINITY;
    for (int j=0;j<n;j++) mm = fmaxf(mm, P[tid][j]);
    float l = 0.f;
    for (int j=0;j<n;j++){ const float p = __expf(P[tid][j]-mm); P[tid][j]=p; l+=p; }
    const float inv = 1.f/l;
    for (int j=0;j<n;j++) P[tid][j] *= inv;
  }
  __syncthreads();
  #pragma unroll
  for (int t=0;t<6;t++){
    const int idx = tid + t*256;
    const int i = idx >> 6, d = idx & 63;
    float s = 0.f;
    for (int j=0;j<n;j++) s = fmaf(P[i][j], Vs[j][d], s);
    Og[base + (size_t)i*DM + d] = s;
  }
}

// ---------------- decoder cross-attention: split-K partials + combine ----------------
__global__ __launch_bounds__(256)
void attn_cross_part(const float* __restrict__ Qg, const float* __restrict__ Kc,
                     const float* __restrict__ Vc, float* __restrict__ opart,
                     float* __restrict__ mlpart)
{
  const int ks = blockIdx.x;
  const int bh = blockIdx.y;
  const int b = bh >> 4, hh = bh & 15;
  __shared__ float Qs[NSTEP][68];
  __shared__ float KVs[CKEYS][68];        // K first, then reused for V
  __shared__ float S[NSTEP][CKEYS+4];
  const int tid = threadIdx.x;
  const size_t qbase = ((size_t)b*NSTEP)*DM + hh*DKH;
  for (int t=tid; t<NSTEP*16; t+=256){
    const int row = t>>4, dq = t&15;
    *(float4*)&Qs[row][dq*4] = *(const float4*)(Qg + qbase + (size_t)row*DM + dq*4);
  }
  const size_t kbase = ((size_t)b*TT + (size_t)ks*CKEYS)*DM + hh*DKH;
  for (int t=tid; t<CKEYS*16; t+=256){
    const int row = t>>4, dq = t&15;
    *(float4*)&KVs[row][dq*4] = *(const float4*)(Kc + kbase + (size_t)row*DM + dq*4);
  }
  __syncthreads();
  #pragma unroll
  for (int t=0;t<12;t++){                 // 24*128 scores
    const int idx = tid + t*256;
    const int i = idx >> 7, j = idx & 127;
    float s0=0.f,s1=0.f,s2=0.f,s3=0.f;
    #pragma unroll
    for (int d=0; d<64; d+=4){
      s0 = fmaf(Qs[i][d+0], KVs[j][d+0], s0);
      s1 = fmaf(Qs[i][d+1], KVs[j][d+1], s1);
      s2 = fmaf(Qs[i][d+2], KVs[j][d+2], s2);
      s3 = fmaf(Qs[i][d+3], KVs[j][d+3], s3);
    }
    S[i][j] = ((s0+s1)+(s2+s3))*0.125f;
  }
  __syncthreads();
  // softmax (24 threads) + concurrently stage V over the K buffer
  for (int t=tid; t<CKEYS*16; t+=256){
    const int row = t>>4, dq = t&15;
    *(float4*)&KVs[row][dq*4] = *(const float4*)(Vc + kbase + (size_t)row*DM + dq*4);
  }
  if (tid < NSTEP){
    float mm=-INFINITY;
    for (int j=0;j<CKEYS;j++) mm = fmaxf(mm, S[tid][j]);
    float l=0.f;
    for (int j=0;j<CKEYS;j++){ const float p=__expf(S[tid][j]-mm); S[tid][j]=p; l+=p; }
    mlpart[((size_t)bh*CSPLIT+ks)*(2*NSTEP) + tid*2+0] = mm;
    mlpart[((size_t)bh*CSPLIT+ks)*(2*NSTEP) + tid*2+1] = l;
  }
  __syncthreads();
  #pragma unroll
  for (int t=0;t<6;t++){
    const int idx = tid + t*256;
    const int i = idx >> 6, d = idx & 63;
    float s=0.f;
    for (int j=0;j<CKEYS;j++) s = fmaf(S[i][j], KVs[j][d], s);
    opart[(((size_t)bh*CSPLIT+ks)*NSTEP + i)*DKH + d] = s;
  }
}

__global__ __launch_bounds__(256)
void attn_cross_comb(const float* __restrict__ opart, const float* __restrict__ mlpart,
                     float* __restrict__ Og)
{
  const int bh = blockIdx.x;
  const int idx = blockIdx.y*256 + threadIdx.x;  // < 24*64
  const int i = idx >> 6, d = idx & 63;
  float M = -INFINITY;
  #pragma unroll
  for (int s=0;s<CSPLIT;s++)
    M = fmaxf(M, mlpart[((size_t)bh*CSPLIT+s)*(2*NSTEP) + i*2]);
  float acc = 0.f, L = 0.f;
  #pragma unroll
  for (int s=0;s<CSPLIT;s++){
    const float mm = mlpart[((size_t)bh*CSPLIT+s)*(2*NSTEP) + i*2+0];
    const float ll = mlpart[((size_t)bh*CSPLIT+s)*(2*NSTEP) + i*2+1];
    const float f = __expf(mm - M);
    acc = fmaf(f, opart[(((size_t)bh*CSPLIT+s)*NSTEP + i)*DKH + d], acc);
    L   = fmaf(f, ll, L);
  }
  const int b = bh >> 4, hh = bh & 15;
  Og[((size_t)b*NSTEP + i)*DM + hh*DKH + d] = acc / L;
}

// ---------------- LayerNorm(x+y)*g+b over rows of 1024 ----------------
__device__ inline float wave_sum(float v){
  #pragma unroll
  for (int off=1; off<64; off<<=1) v += __shfl_xor(v, off, 64);
  return v;
}

__global__ __launch_bounds__(256)
void ln_add(const float* __restrict__ X, const float* __restrict__ Y,
            const float* __restrict__ g, const float* __restrict__ be,
            float* __restrict__ Out)
{
  const size_t row = blockIdx.x;
  const int tid = threadIdx.x;
  const float4 a = *(const float4*)(X + row*DM + tid*4);
  const float4 b = *(const float4*)(Y + row*DM + tid*4);
  const float v0=a.x+b.x, v1=a.y+b.y, v2=a.z+b.z, v3=a.w+b.w;
  float s = v0+v1+v2+v3;
  float q = v0*v0+v1*v1+v2*v2+v3*v3;
  s = wave_sum(s); q = wave_sum(q);
  __shared__ float rs[4], rq[4];
  if ((tid&63)==0){ rs[tid>>6]=s; rq[tid>>6]=q; }
  __syncthreads();
  const float S = rs[0]+rs[1]+rs[2]+rs[3];
  const float Q = rq[0]+rq[1]+rq[2]+rq[3];
  const float mean = S * (1.f/DM);
  const float var  = Q * (1.f/DM) - mean*mean;
  const float rstd = rsqrtf(var + 1e-5f);
  const float4 gv = *(const float4*)(g  + tid*4);
  const float4 bv = *(const float4*)(be + tid*4);
  float4 o;
  o.x = (v0-mean)*rstd*gv.x + bv.x;
  o.y = (v1-mean)*rstd*gv.y + bv.y;
  o.z = (v2-mean)*rstd*gv.z + bv.z;
  o.w = (v3-mean)*rstd*gv.w + bv.w;
  *(float4*)(Out + row*DM + tid*4) = o;
}

// ---------------- final projection + token embedding append ----------------
__global__ __launch_bounds__(256)
void out_step(const float* __restrict__ Dv, const float* __restrict__ outW,
              const float* __restrict__ outB, const float* __restrict__ tembW,
              const float* __restrict__ tembB, float* __restrict__ dout,
              float* __restrict__ tok, int s)
{
  const int b = blockIdx.x;
  const int tid = threadIdx.x;
  const float* drow = Dv + ((size_t)(b*NSTEP + s))*DM;
  const float4 dv = *(const float4*)(drow + tid*4);
  const float4 wv = *(const float4*)(outW + tid*4);
  float part = dv.x*wv.x + dv.y*wv.y + dv.z*wv.z + dv.w*wv.w;
  part = wave_sum(part);
  __shared__ float red[4];
  __shared__ float stepv;
  if ((tid&63)==0) red[tid>>6] = part;
  __syncthreads();
  if (tid==0) stepv = red[0]+red[1]+red[2]+red[3] + outB[0];
  __syncthreads();
  const float sv = stepv;
  if (tid==0) dout[b*NSTEP + s] = sv;
  if (s+1 < NSTEP) {
    const int d = tid*4;
    const float4 tw = *(const float4*)(tembW + d);
    const float4 tb = *(const float4*)(tembB + d);
    float4 e;
    e.x = fmaf(sv, tw.x, tb.x); e.y = fmaf(sv, tw.y, tb.y);
    e.z = fmaf(sv, tw.z, tb.z); e.w = fmaf(sv, tw.w, tb.w);
    *(float4*)(tok + ((size_t)(b*NSTEP + s + 1))*DM + d) = e;
  }
}

// ---------------- orchestration ----------------
extern "C" void kernel_launch(void* const* d_in, const int* in_sizes, int n_in,
                              void* d_out, int out_size, void* d_ws, size_t ws_size,
                              hipStream_t stream)
{
  (void)in_sizes; (void)n_in; (void)out_size; (void)ws_size;
  const float* x      = (const float*)d_in[0];
  const float* in_W   = (const float*)d_in[1];
  const float* in_b   = (const float*)d_in[2];
  const float* enc_Wq = (const float*)d_in[3];
  const float* enc_bq = (const float*)d_in[4];
  const float* enc_Wk = (const float*)d_in[5];
  const float* enc_bk = (const float*)d_in[6];
  const float* enc_Wv = (const float*)d_in[7];
  const float* enc_bv = (const float*)d_in[8];
  const float* enc_Wo = (const float*)d_in[9];
  const float* enc_bo = (const float*)d_in[10];
  const float* dec_Wq = (const float*)d_in[11];
  const float* dec_bq = (const float*)d_in[12];
  const float* dec_Wk = (const float*)d_in[13];
  const float* dec_bk = (const float*)d_in[14];
  const float* dec_Wv = (const float*)d_in[15];
  const float* dec_bv = (const float*)d_in[16];
  const float* dec_Wo = (const float*)d_in[17];
  const float* dec_bo = (const float*)d_in[18];
  const float* ffe_W1 = (const float*)d_in[19];
  const float* ffe_b1 = (const float*)d_in[20];
  const float* ffe_W2 = (const float*)d_in[21];
  const float* ffe_b2 = (const float*)d_in[22];
  const float* ffd_W1 = (const float*)d_in[23];
  const float* ffd_b1 = (const float*)d_in[24];
  const float* ffd_W2 = (const float*)d_in[25];
  const float* ffd_b2 = (const float*)d_in[26];
  const float* ne_g   = (const float*)d_in[27];
  const float* ne_b   = (const float*)d_in[28];
  const float* nd_g   = (const float*)d_in[29];
  const float* nd_b   = (const float*)d_in[30];
  const float* out_W  = (const float*)d_in[31];
  const float* out_b  = (const float*)d_in[32];
  const float* temb_W = (const float*)d_in[33];
  const float* temb_b = (const float*)d_in[34];
  float* dout = (float*)d_out;

  float* ws = (float*)d_ws;
  size_t off = 0;
  auto alloc = [&](size_t n){ float* p = ws + off; off += n; return p; };
  float* pe   = alloc((size_t)TT*DM);
  float* h    = alloc((size_t)BT*DM);
  float* t0   = alloc((size_t)BT*DM);   // t0..t3 contiguous; also alias for FFN hidden
  float* t1   = alloc((size_t)BT*DM);
  float* t2   = alloc((size_t)BT*DM);
  float* t3   = alloc((size_t)BT*DM);
  float* t4   = alloc((size_t)BT*DM);
  float* kc   = alloc((size_t)NL*BT*DM);
  float* vc   = alloc((size_t)NL*BT*DM);
  float* tok  = alloc((size_t)MD*DM);
  float* dbuf = alloc((size_t)MD*DM);
  float* dq   = alloc((size_t)MD*DM);
  float* dk   = alloc((size_t)MD*DM);
  float* dv_  = alloc((size_t)MD*DM);
  float* dab  = alloc((size_t)MD*DM);
  float* dmid = alloc((size_t)MD*DFFN);
  float* dffo = alloc((size_t)MD*DM);
  float* part = alloc((size_t)4*1024*1024);
  float* opart= alloc((size_t)BB*NH*CSPLIT*NSTEP*DKH);
  float* mlp  = alloc((size_t)BB*NH*CSPLIT*2*NSTEP);
  float* fm   = t0;  // encoder FFN hidden (BT x DFFN) aliases t0..t3 (dead during FFN)
  (void)t1; (void)t2; (void)t3;

  pe_kernel<<<TT, 256, 0, stream>>>(pe);
  zero_kernel<<<(MD*DM+255)/256, 256, 0, stream>>>(tok, MD*DM);

  // input projection (K=64) + positional encoding
  gemm_nt<0><<<dim3(BT/128, DM/128), 256, 0, stream>>>(x, in_W, in_b, h, BT, DM, 64);
  add_pe_enc<<<BT, 256, 0, stream>>>(h, pe);

  // ---- encoder ----
  for (int l=0; l<NL; ++l) {
    const size_t wo = (size_t)l*DM*DM, bo_ = (size_t)l*DM;
    gemm_nt<0><<<dim3(32,8),256,0,stream>>>(h, enc_Wq+wo, enc_bq+bo_, t0, BT, DM, DM);
    gemm_nt<0><<<dim3(32,8),256,0,stream>>>(h, enc_Wk+wo, enc_bk+bo_, t1, BT, DM, DM);
    gemm_nt<0><<<dim3(32,8),256,0,stream>>>(h, enc_Wv+wo, enc_bv+bo_, t2, BT, DM, DM);
    attn_enc<<<dim3(TT/256, BB*NH),256,0,stream>>>(t0, t1, t2, t3);
    gemm_nt<0><<<dim3(32,8),256,0,stream>>>(t3, enc_Wo+wo, enc_bo+bo_, h, BT, DM, DM);  // no residual
    gemm_nt<1><<<dim3(32,32),256,0,stream>>>(h, ffe_W1, ffe_b1, fm, BT, DFFN, DM);
    gemm_nt<0><<<dim3(32,8),256,0,stream>>>(fm, ffe_W2, ffe_b2, t4, BT, DM, DFFN);
    ln_add<<<BT,256,0,stream>>>(h, t4, ne_g, ne_b, h);
  }

  // ---- cross-attention K/V cache (h is fixed; weights shared across steps) ----
  for (int l=0; l<NL; ++l) {
    const size_t wo = (size_t)l*DM*DM, bo_ = (size_t)l*DM;
    gemm_nt<0><<<dim3(32,8),256,0,stream>>>(h, dec_Wk+wo, dec_bk+bo_, kc+(size_t)l*BT*DM, BT, DM, DM);
    gemm_nt<0><<<dim3(32,8),256,0,stream>>>(h, dec_Wv+wo, dec_bv+bo_, vc+(size_t)l*BT*DM, BT, DM, DM);
  }

  // ---- decoder (fixed 96-row padding; attention masked to n valid tokens) ----
  for (int s=0; s<NSTEP; ++s) {
    const int n = s+1;
    dec_prep<<<MD,256,0,stream>>>(dbuf, tok, pe);
    for (int l=0; l<NL; ++l) {
      const size_t wo = (size_t)l*DM*DM, bo_ = (size_t)l*DM;
      // self-attn QKV (fused 3-in-1 launch)
      gemm_skinny<<<dim3(16,8,3),256,0,stream>>>(dbuf, dec_Wq+wo, dec_Wk+wo, dec_Wv+wo, part, DM, DM, 8);
      reduce_part<0><<<dim3(384,3),256,0,stream>>>(part, dec_bq+bo_, dec_bk+bo_, dec_bv+bo_, dq, dk, dv_, DM, 8);
      attn_dec_self<<<BB*NH,256,0,stream>>>(dq, dk, dv_, dab, n);
      gemm_skinny<<<dim3(16,8,1),256,0,stream>>>(dab, dec_Wo+wo, dec_Wo+wo, dec_Wo+wo, part, DM, DM, 8);
      reduce_part<0><<<dim3(384,1),256,0,stream>>>(part, dec_bo+bo_, dec_bo+bo_, dec_bo+bo_, dbuf, dbuf, dbuf, DM, 8);
      // cross-attn (KV cached)
      gemm_skinny<<<dim3(16,8,1),256,0,stream>>>(dbuf, dec_Wq+wo, dec_Wq+wo, dec_Wq+wo, part, DM, DM, 8);
      reduce_part<0><<<dim3(384,1),256,0,stream>>>(part, dec_bq+bo_, dec_bq+bo_, dec_bq+bo_, dq, dq, dq, DM, 8);
      attn_cross_part<<<dim3(CSPLIT, BB*NH),256,0,stream>>>(dq, kc+(size_t)l*BT*DM, vc+(size_t)l*BT*DM, opart, mlp);
      attn_cross_comb<<<dim3(BB*NH, 6),256,0,stream>>>(opart, mlp, dab);
      gemm_skinny<<<dim3(16,8,1),256,0,stream>>>(dab, dec_Wo+wo, dec_Wo+wo, dec_Wo+wo, part, DM, DM, 8);
      reduce_part<0><<<dim3(384,1),256,0,stream>>>(part, dec_bo+bo_, dec_bo+bo_, dec_bo+bo_, dbuf, dbuf, dbuf, DM, 8);
      // FFN + LN(residual)
      gemm_skinny<<<dim3(64,8,1),256,0,stream>>>(dbuf, ffd_W1, ffd_W1, ffd_W1, part, DFFN, DM, 8);
      reduce_part<1><<<dim3(1536,1),256,0,stream>>>(part, ffd_b1, ffd_b1, ffd_b1, dmid, dmid, dmid, DFFN, 8);
      gemm_skinny<<<dim3(16,16,1),256,0,stream>>>(dmid, ffd_W2, ffd_W2, ffd_W2, part, DM, DFFN, 16);
      reduce_part<0><<<dim3(384,1),256,0,stream>>>(part, ffd_b2, ffd_b2, ffd_b2, dffo, dffo, dffo, DM, 16);
      ln_add<<<MD,256,0,stream>>>(dbuf, dffo, nd_g, nd_b, dbuf);
    }
    out_step<<<BB,256,0,stream>>>(dbuf, out_W, out_b, temb_W, temb_b, dout, tok, s);
  }
}

// Round 3
// 20297.949 us; speedup vs baseline: 1.3172x; 1.3172x over previous
//
#include <hip/hip_runtime.h>
#include <math.h>

#define DM    1024
#define NH    16
#define DKH   64
#define NL    4
#define DFFN  4096
#define BB    4
#define TT    1024
#define NSTEP 24
#define BT    (BB*TT)      // 4096 encoder rows
#define MD    (BB*NSTEP)   // 96 decoder rows (fixed padding; only first n valid per step)
#define CSPLIT 8
#define CKEYS  (TT/CSPLIT) // 128 keys per cross-attn split

typedef __attribute__((ext_vector_type(8))) short s16x8;
typedef __attribute__((ext_vector_type(4))) short s16x4;
typedef __attribute__((ext_vector_type(4))) float f32x4;

__device__ inline short f2b(float f){
  unsigned u = __float_as_uint(f);
  u += 0x7fffu + ((u>>16)&1u);          // round-to-nearest-even
  return (short)(u>>16);
}
__device__ inline float b2f(short h){
  return __uint_as_float(((unsigned)(unsigned short)h)<<16);
}

// ---------------- f32 -> (hi,lo) bf16 split ----------------
__global__ __launch_bounds__(256)
void split_kernel(const float* __restrict__ X, short* __restrict__ Hi,
                  short* __restrict__ Lo, int n8)
{
  const size_t i = (size_t)blockIdx.x*256 + threadIdx.x;
  if (i >= (size_t)n8) return;
  const float4 v0 = *(const float4*)(X + i*8);
  const float4 v1 = *(const float4*)(X + i*8 + 4);
  const float f[8] = {v0.x,v0.y,v0.z,v0.w,v1.x,v1.y,v1.z,v1.w};
  s16x8 hv, lv;
  #pragma unroll
  for (int e=0;e<8;e++){
    const short h = f2b(f[e]);
    hv[e] = h;
    lv[e] = f2b(f[e] - b2f(h));
  }
  *(s16x8*)(Hi + i*8) = hv;
  *(s16x8*)(Lo + i*8) = lv;
}

__global__ void zero_kernel(float* __restrict__ p, int n) {
  int i = blockIdx.x*256 + threadIdx.x;
  if (i < n) p[i] = 0.f;
}

// h[row] + pe[row%TT] -> split bf16
__global__ __launch_bounds__(256)
void add_pe_split(const float* __restrict__ h, short* __restrict__ Hi,
                  short* __restrict__ Lo)
{
  const int row = blockIdx.x;
  const int pos = row & (TT-1);
  const int d = threadIdx.x*4;
  const float4 a = *(const float4*)(h + (size_t)row*DM + d);
  const float c1 = -9.210340371976184f / 1024.0f;
  const float e0 = expf((float)d * c1);
  const float e1 = expf((float)(d+2) * c1);
  const float a0 = (float)pos * e0, a1 = (float)pos * e1;
  const float v[4] = {a.x + sinf(a0), a.y + cosf(a0), a.z + sinf(a1), a.w + cosf(a1)};
  s16x4 hv, lv;
  #pragma unroll
  for (int e=0;e<4;e++){
    const short hb = f2b(v[e]);
    hv[e] = hb;
    lv[e] = f2b(v[e] - b2f(hb));
  }
  *(s16x4*)(Hi + (size_t)row*DM + d) = hv;
  *(s16x4*)(Lo + (size_t)row*DM + d) = lv;
}

// dbuf[b,i] = tok[b,i] + pe[i] (f32, decoder)
__global__ __launch_bounds__(256)
void dec_prep(float* __restrict__ dbuf, const float* __restrict__ tok)
{
  const int row = blockIdx.x;           // b*NSTEP + i
  const int i = row % NSTEP;
  const int d = threadIdx.x*4;
  const float4 a = *(const float4*)(tok + (size_t)row*DM + d);
  const float c1 = -9.210340371976184f / 1024.0f;
  const float e0 = expf((float)d * c1);
  const float e1 = expf((float)(d+2) * c1);
  const float a0 = (float)i * e0, a1 = (float)i * e1;
  float4 o;
  o.x = a.x + sinf(a0); o.y = a.y + cosf(a0);
  o.z = a.z + sinf(a1); o.w = a.w + cosf(a1);
  *(float4*)(dbuf + (size_t)row*DM + d) = o;
}

// ---------------- split-bf16 MFMA GEMM: C[M,N] = A[M,K] @ W[N,K]^T + bias ----------
// A,W given as (hi,lo) bf16 pairs; 3 MFMAs per fragment pair -> ~fp32 accuracy.
// 128x128 tile, 256 threads = 4 waves (2x2), BK=32, mfma_f32_16x16x32_bf16.
// OUT_MODE: 0 = f32 C; 1 = split (Chi,Clo); 2 = both; 3 = plain-bf16 Chi only.
template<int ACT, int OUT_MODE>
__global__ __launch_bounds__(256, 2)
void gemm_split(const short* __restrict__ Ahi, const short* __restrict__ Alo,
                const short* __restrict__ Bhi, const short* __restrict__ Blo,
                const float* __restrict__ bias,
                float* __restrict__ C, short* __restrict__ Chi, short* __restrict__ Clo,
                int M, int N, int K)
{
  __shared__ __align__(16) short lA[2][128][40];   // [hi/lo][row][k], 80B row stride
  __shared__ __align__(16) short lB[2][128][40];
  const int tid = threadIdx.x;
  const int m0 = blockIdx.x*128, n0 = blockIdx.y*128;
  const int lane = tid & 63, w = tid >> 6;
  const int wr = w >> 1, wc = w & 1;           // wave quadrant (64x64)
  const int fr = lane & 15, fq = lane >> 4;    // frag row/col, k-quarter

  f32x4 acc[4][4];
  #pragma unroll
  for (int i=0;i<4;i++)
    #pragma unroll
    for (int j=0;j<4;j++) acc[i][j] = (f32x4){0.f,0.f,0.f,0.f};

  for (int k0 = 0; k0 < K; k0 += 32) {
    __syncthreads();
    #pragma unroll
    for (int j=0;j<2;j++){
      const int cc = tid + j*256;              // 0..511
      const int row = cc >> 2, kq = cc & 3;
      const size_t ga = (size_t)(m0+row)*K + k0 + kq*8;
      const size_t gb = (size_t)(n0+row)*K + k0 + kq*8;
      *(s16x8*)&lA[0][row][kq*8] = *(const s16x8*)(Ahi + ga);
      *(s16x8*)&lA[1][row][kq*8] = *(const s16x8*)(Alo + ga);
      *(s16x8*)&lB[0][row][kq*8] = *(const s16x8*)(Bhi + gb);
      *(s16x8*)&lB[1][row][kq*8] = *(const s16x8*)(Blo + gb);
    }
    __syncthreads();
    s16x8 ah[4], al[4], bh[4], bl[4];
    #pragma unroll
    for (int i=0;i<4;i++){
      ah[i] = *(const s16x8*)&lA[0][wr*64+i*16+fr][fq*8];
      al[i] = *(const s16x8*)&lA[1][wr*64+i*16+fr][fq*8];
    }
    #pragma unroll
    for (int j=0;j<4;j++){
      bh[j] = *(const s16x8*)&lB[0][wc*64+j*16+fr][fq*8];
      bl[j] = *(const s16x8*)&lB[1][wc*64+j*16+fr][fq*8];
    }
    #pragma unroll
    for (int i=0;i<4;i++)
      #pragma unroll
      for (int j=0;j<4;j++){
        acc[i][j] = __builtin_amdgcn_mfma_f32_16x16x32_bf16(ah[i], bh[j], acc[i][j], 0,0,0);
        acc[i][j] = __builtin_amdgcn_mfma_f32_16x16x32_bf16(ah[i], bl[j], acc[i][j], 0,0,0);
        acc[i][j] = __builtin_amdgcn_mfma_f32_16x16x32_bf16(al[i], bh[j], acc[i][j], 0,0,0);
      }
  }
  // epilogue: C/D layout col=lane&15, row=(lane>>4)*4+reg  [verified m89]
  #pragma unroll
  for (int j=0;j<4;j++){
    const int col = n0 + wc*64 + j*16 + fr;
    const float bv = bias[col];
    #pragma unroll
    for (int i=0;i<4;i++){
      const int row0 = m0 + wr*64 + i*16 + fq*4;
      #pragma unroll
      for (int r=0;r<4;r++){
        float v = acc[i][j][r] + bv;
        if (ACT==1) v = fmaxf(v, 0.f);
        const size_t idx = (size_t)(row0+r)*N + col;
        if (OUT_MODE==0 || OUT_MODE==2) C[idx] = v;
        if (OUT_MODE==1 || OUT_MODE==2){
          const short hb = f2b(v);
          Chi[idx] = hb;
          Clo[idx] = f2b(v - b2f(hb));
        }
        if (OUT_MODE==3) Chi[idx] = f2b(v);
      }
    }
  }
}

// ---------------- skinny GEMM (M=96) with K-split partials (decoder) -------------
__global__ __launch_bounds__(256)
void gemm_skinny(const float* __restrict__ A,
                 const float* __restrict__ W0, const float* __restrict__ W1,
                 const float* __restrict__ W2,
                 float* __restrict__ part, int N, int K, int KS)
{
  const float* Wt = (blockIdx.z==0) ? W0 : (blockIdx.z==1 ? W1 : W2);
  float* P = part + ((size_t)blockIdx.z*KS + blockIdx.y)*(size_t)MD*N;
  const int KK = K / KS;
  const int kbase = blockIdx.y * KK;
  const int n0 = blockIdx.x * 64;
  __shared__ float As[MD][68];
  __shared__ float Ws[64][68];
  const int tid = threadIdx.x;
  const int cg = tid & 15, rg = tid >> 4;
  float acc[6][4];
  #pragma unroll
  for (int i=0;i<6;i++)
    #pragma unroll
    for (int j=0;j<4;j++) acc[i][j]=0.f;

  for (int kc=0; kc<KK; kc+=64) {
    const int k0 = kbase + kc;
    __syncthreads();
    #pragma unroll
    for (int t=0;t<6;t++) {
      const int fi = tid + t*256; const int row = fi>>4, kq = fi&15;
      *(float4*)&As[row][kq*4] = *(const float4*)(A + (size_t)row*K + k0 + kq*4);
    }
    #pragma unroll
    for (int t=0;t<4;t++) {
      const int fi = tid + t*256; const int row = fi>>4, kq = fi&15;
      *(float4*)&Ws[row][kq*4] = *(const float4*)(Wt + (size_t)(n0+row)*K + k0 + kq*4);
    }
    __syncthreads();
    #pragma unroll 4
    for (int kk=0;kk<64;kk++) {
      float wv[4], a[6];
      #pragma unroll
      for (int j=0;j<4;j++) wv[j] = Ws[cg + j*16][kk];
      #pragma unroll
      for (int i=0;i<6;i++) a[i] = As[rg*6+i][kk];
      #pragma unroll
      for (int i=0;i<6;i++)
        #pragma unroll
        for (int j=0;j<4;j++) acc[i][j] = fmaf(a[i], wv[j], acc[i][j]);
    }
  }
  #pragma unroll
  for (int i=0;i<6;i++)
    #pragma unroll
    for (int j=0;j<4;j++)
      P[(size_t)(rg*6+i)*N + n0 + cg + j*16] = acc[i][j];
}

template<int ACT>
__global__ __launch_bounds__(256)
void reduce_part(const float* __restrict__ part,
                 const float* __restrict__ b0, const float* __restrict__ b1,
                 const float* __restrict__ b2,
                 float* __restrict__ o0, float* __restrict__ o1, float* __restrict__ o2,
                 int N, int KS)
{
  const int idx = blockIdx.x*256 + threadIdx.x;
  const float* P = part + (size_t)blockIdx.y*KS*(size_t)MD*N;
  const float* bias = (blockIdx.y==0)?b0:(blockIdx.y==1?b1:b2);
  float* out = (blockIdx.y==0)?o0:(blockIdx.y==1?o1:o2);
  float s = 0.f;
  for (int ks=0; ks<KS; ks++) s += P[(size_t)ks*MD*N + idx];
  s += bias[idx & (N-1)];
  if (ACT==1) s = fmaxf(s, 0.f);
  out[idx] = s;
}

// ---------------- encoder self-attention (flash, thread-per-q-row, split out) ----
__global__ __launch_bounds__(256)
void attn_enc(const float* __restrict__ Qg, const float* __restrict__ Kg,
              const float* __restrict__ Vg, short* __restrict__ Ohi,
              short* __restrict__ Olo)
{
  const int bh = blockIdx.y;
  const int b = bh >> 4, hh = bh & 15;
  const int row = blockIdx.x*256 + threadIdx.x;
  const size_t base = ((size_t)b*TT)*DM + hh*DKH;
  float q[64];
  {
    const float* qp = Qg + base + (size_t)row*DM;
    #pragma unroll
    for (int d4=0; d4<16; d4++){
      const float4 v = *(const float4*)(qp + d4*4);
      q[d4*4+0]=v.x; q[d4*4+1]=v.y; q[d4*4+2]=v.z; q[d4*4+3]=v.w;
    }
  }
  float o[64];
  #pragma unroll
  for (int d=0;d<64;d++) o[d]=0.f;
  float m = -INFINITY, l = 0.f;
  __shared__ float Ks[64][68];
  __shared__ float Vs[64][68];
  for (int kt=0; kt<TT; kt+=64) {
    __syncthreads();
    #pragma unroll
    for (int t=0;t<4;t++){
      const int fi = threadIdx.x + t*256;
      const int j = fi>>4, dq = fi&15;
      *(float4*)&Ks[j][dq*4] = *(const float4*)(Kg + base + (size_t)(kt+j)*DM + dq*4);
      *(float4*)&Vs[j][dq*4] = *(const float4*)(Vg + base + (size_t)(kt+j)*DM + dq*4);
    }
    __syncthreads();
    for (int j=0;j<64;j++){
      float s0=0.f,s1=0.f,s2=0.f,s3=0.f;
      #pragma unroll
      for (int d=0; d<64; d+=4){
        s0 = fmaf(q[d+0], Ks[j][d+0], s0);
        s1 = fmaf(q[d+1], Ks[j][d+1], s1);
        s2 = fmaf(q[d+2], Ks[j][d+2], s2);
        s3 = fmaf(q[d+3], Ks[j][d+3], s3);
      }
      const float s = ((s0+s1)+(s2+s3)) * 0.125f;
      if (s > m) {
        const float f = __expf(m - s);
        l *= f;
        #pragma unroll
        for (int d=0;d<64;d++) o[d] *= f;
        m = s;
      }
      const float p = __expf(s - m);
      l += p;
      #pragma unroll
      for (int d=0;d<64;d++) o[d] = fmaf(p, Vs[j][d], o[d]);
    }
  }
  const float inv = 1.f / l;
  #pragma unroll
  for (int d8=0; d8<8; d8++){
    s16x8 hv, lv;
    #pragma unroll
    for (int e=0;e<8;e++){
      const float f = o[d8*8+e]*inv;
      const short hb = f2b(f);
      hv[e] = hb;
      lv[e] = f2b(f - b2f(hb));
    }
    *(s16x8*)(Ohi + base + (size_t)row*DM + d8*8) = hv;
    *(s16x8*)(Olo + base + (size_t)row*DM + d8*8) = lv;
  }
}

// ---------------- decoder self-attention (tiny, one block per (b,h)) ----------------
__global__ __launch_bounds__(256)
void attn_dec_self(const float* __restrict__ Qg, const float* __restrict__ Kg,
                   const float* __restrict__ Vg, float* __restrict__ Og, int n)
{
  const int b = blockIdx.x >> 4, hh = blockIdx.x & 15;
  const size_t base = ((size_t)b*NSTEP)*DM + hh*DKH;
  __shared__ float Qs[NSTEP][68], Ks[NSTEP][68], Vs[NSTEP][68];
  __shared__ float P[NSTEP][28];
  const int tid = threadIdx.x;
  for (int t = tid; t < 3*NSTEP*16; t += 256) {
    const int tensor = t / (NSTEP*16);
    const int fi = t - tensor*(NSTEP*16);
    const int row = fi >> 4, dq = fi & 15;
    const float* src = (tensor==0?Qg:(tensor==1?Kg:Vg)) + base + (size_t)row*DM + dq*4;
    float (*dst)[68] = (tensor==0?Qs:(tensor==1?Ks:Vs));
    *(float4*)&dst[row][dq*4] = *(const float4*)src;
  }
  __syncthreads();
  for (int idx = tid; idx < NSTEP*n; idx += 256) {
    const int i = idx / n, j = idx - i*n;
    float s0=0.f,s1=0.f,s2=0.f,s3=0.f;
    #pragma unroll
    for (int d=0; d<64; d+=4){
      s0 = fmaf(Qs[i][d+0], Ks[j][d+0], s0);
      s1 = fmaf(Qs[i][d+1], Ks[j][d+1], s1);
      s2 = fmaf(Qs[i][d+2], Ks[j][d+2], s2);
      s3 = fmaf(Qs[i][d+3], Ks[j][d+3], s3);
    }
    P[i][j] = ((s0+s1)+(s2+s3))*0.125f;
  }
  __syncthreads();
  if (tid < NSTEP) {
    float mm = -INFINITY;
    for (int j=0;j<n;j++) mm = fmaxf(mm, P[tid][j]);
    float l = 0.f;
    for (int j=0;j<n;j++){ const float p = __expf(P[tid][j]-mm); P[tid][j]=p; l+=p; }
    const float inv = 1.f/l;
    for (int j=0;j<n;j++) P[tid][j] *= inv;
  }
  __syncthreads();
  #pragma unroll
  for (int t=0;t<6;t++){
    const int idx = tid + t*256;
    const int i = idx >> 6, d = idx & 63;
    float s = 0.f;
    for (int j=0;j<n;j++) s = fmaf(P[i][j], Vs[j][d], s);
    Og[base + (size_t)i*DM + d] = s;
  }
}

// ---------------- decoder cross-attention (bf16 K/V cache): split-K + combine -----
__global__ __launch_bounds__(256)
void attn_cross_part(const float* __restrict__ Qg, const short* __restrict__ Kc,
                     const short* __restrict__ Vc, float* __restrict__ opart,
                     float* __restrict__ mlpart)
{
  const int ks = blockIdx.x;
  const int bh = blockIdx.y;
  const int b = bh >> 4, hh = bh & 15;
  __shared__ float Qs[NSTEP][68];
  __shared__ float KVs[CKEYS][68];        // K first, then reused for V
  __shared__ float S[NSTEP][CKEYS+4];
  const int tid = threadIdx.x;
  const size_t qbase = ((size_t)b*NSTEP)*DM + hh*DKH;
  for (int t=tid; t<NSTEP*16; t+=256){
    const int row = t>>4, dq = t&15;
    *(float4*)&Qs[row][dq*4] = *(const float4*)(Qg + qbase + (size_t)row*DM + dq*4);
  }
  const size_t kbase = ((size_t)b*TT + (size_t)ks*CKEYS)*DM + hh*DKH;
  for (int t=tid; t<CKEYS*8; t+=256){
    const int row = t>>3, d8 = t&7;
    const s16x8 v = *(const s16x8*)(Kc + kbase + (size_t)row*DM + d8*8);
    #pragma unroll
    for (int e=0;e<8;e++) KVs[row][d8*8+e] = b2f(v[e]);
  }
  __syncthreads();
  #pragma unroll
  for (int t=0;t<12;t++){
    const int idx = tid + t*256;
    const int i = idx >> 7, j = idx & 127;
    float s0=0.f,s1=0.f,s2=0.f,s3=0.f;
    #pragma unroll
    for (int d=0; d<64; d+=4){
      s0 = fmaf(Qs[i][d+0], KVs[j][d+0], s0);
      s1 = fmaf(Qs[i][d+1], KVs[j][d+1], s1);
      s2 = fmaf(Qs[i][d+2], KVs[j][d+2], s2);
      s3 = fmaf(Qs[i][d+3], KVs[j][d+3], s3);
    }
    S[i][j] = ((s0+s1)+(s2+s3))*0.125f;
  }
  __syncthreads();
  // stage V over the K buffer while 24 threads do softmax
  for (int t=tid; t<CKEYS*8; t+=256){
    const int row = t>>3, d8 = t&7;
    const s16x8 v = *(const s16x8*)(Vc + kbase + (size_t)row*DM + d8*8);
    #pragma unroll
    for (int e=0;e<8;e++) KVs[row][d8*8+e] = b2f(v[e]);
  }
  if (tid < NSTEP){
    float mm=-INFINITY;
    for (int j=0;j<CKEYS;j++) mm = fmaxf(mm, S[tid][j]);
    float l=0.f;
    for (int j=0;j<CKEYS;j++){ const float p=__expf(S[tid][j]-mm); S[tid][j]=p; l+=p; }
    mlpart[((size_t)bh*CSPLIT+ks)*(2*NSTEP) + tid*2+0] = mm;
    mlpart[((size_t)bh*CSPLIT+ks)*(2*NSTEP) + tid*2+1] = l;
  }
  __syncthreads();
  #pragma unroll
  for (int t=0;t<6;t++){
    const int idx = tid + t*256;
    const int i = idx >> 6, d = idx & 63;
    float s=0.f;
    for (int j=0;j<CKEYS;j++) s = fmaf(S[i][j], KVs[j][d], s);
    opart[(((size_t)bh*CSPLIT+ks)*NSTEP + i)*DKH + d] = s;
  }
}

__global__ __launch_bounds__(256)
void attn_cross_comb(const float* __restrict__ opart, const float* __restrict__ mlpart,
                     float* __restrict__ Og)
{
  const int bh = blockIdx.x;
  const int idx = blockIdx.y*256 + threadIdx.x;
  const int i = idx >> 6, d = idx & 63;
  float M = -INFINITY;
  #pragma unroll
  for (int s=0;s<CSPLIT;s++)
    M = fmaxf(M, mlpart[((size_t)bh*CSPLIT+s)*(2*NSTEP) + i*2]);
  float acc = 0.f, L = 0.f;
  #pragma unroll
  for (int s=0;s<CSPLIT;s++){
    const float mm = mlpart[((size_t)bh*CSPLIT+s)*(2*NSTEP) + i*2+0];
    const float ll = mlpart[((size_t)bh*CSPLIT+s)*(2*NSTEP) + i*2+1];
    const float f = __expf(mm - M);
    acc = fmaf(f, opart[(((size_t)bh*CSPLIT+s)*NSTEP + i)*DKH + d], acc);
    L   = fmaf(f, ll, L);
  }
  const int b = bh >> 4, hh = bh & 15;
  Og[((size_t)b*NSTEP + i)*DM + hh*DKH + d] = acc / L;
}

// ---------------- LayerNorm ----------------
__device__ inline float wave_sum(float v){
  #pragma unroll
  for (int off=1; off<64; off<<=1) v += __shfl_xor(v, off, 64);
  return v;
}

// decoder version: f32 out
__global__ __launch_bounds__(256)
void ln_add(const float* __restrict__ X, const float* __restrict__ Y,
            const float* __restrict__ g, const float* __restrict__ be,
            float* __restrict__ Out)
{
  const size_t row = blockIdx.x;
  const int tid = threadIdx.x;
  const float4 a = *(const float4*)(X + row*DM + tid*4);
  const float4 b = *(const float4*)(Y + row*DM + tid*4);
  const float v0=a.x+b.x, v1=a.y+b.y, v2=a.z+b.z, v3=a.w+b.w;
  float s = v0+v1+v2+v3;
  float q = v0*v0+v1*v1+v2*v2+v3*v3;
  s = wave_sum(s); q = wave_sum(q);
  __shared__ float rs[4], rq[4];
  if ((tid&63)==0){ rs[tid>>6]=s; rq[tid>>6]=q; }
  __syncthreads();
  const float S = rs[0]+rs[1]+rs[2]+rs[3];
  const float Q = rq[0]+rq[1]+rq[2]+rq[3];
  const float mean = S * (1.f/DM);
  const float var  = Q * (1.f/DM) - mean*mean;
  const float rstd = rsqrtf(var + 1e-5f);
  const float4 gv = *(const float4*)(g  + tid*4);
  const float4 bv = *(const float4*)(be + tid*4);
  float4 o;
  o.x = (v0-mean)*rstd*gv.x + bv.x;
  o.y = (v1-mean)*rstd*gv.y + bv.y;
  o.z = (v2-mean)*rstd*gv.z + bv.z;
  o.w = (v3-mean)*rstd*gv.w + bv.w;
  *(float4*)(Out + row*DM + tid*4) = o;
}

// encoder version: split bf16 out
__global__ __launch_bounds__(256)
void ln_add_split(const float* __restrict__ X, const float* __restrict__ Y,
                  const float* __restrict__ g, const float* __restrict__ be,
                  short* __restrict__ Ohi, short* __restrict__ Olo)
{
  const size_t row = blockIdx.x;
  const int tid = threadIdx.x;
  const float4 a = *(const float4*)(X + row*DM + tid*4);
  const float4 b = *(const float4*)(Y + row*DM + tid*4);
  const float v0=a.x+b.x, v1=a.y+b.y, v2=a.z+b.z, v3=a.w+b.w;
  float s = v0+v1+v2+v3;
  float q = v0*v0+v1*v1+v2*v2+v3*v3;
  s = wave_sum(s); q = wave_sum(q);
  __shared__ float rs[4], rq[4];
  if ((tid&63)==0){ rs[tid>>6]=s; rq[tid>>6]=q; }
  __syncthreads();
  const float S = rs[0]+rs[1]+rs[2]+rs[3];
  const float Q = rq[0]+rq[1]+rq[2]+rq[3];
  const float mean = S * (1.f/DM);
  const float var  = Q * (1.f/DM) - mean*mean;
  const float rstd = rsqrtf(var + 1e-5f);
  const float4 gv = *(const float4*)(g  + tid*4);
  const float4 bv = *(const float4*)(be + tid*4);
  const float v[4] = {(v0-mean)*rstd*gv.x + bv.x, (v1-mean)*rstd*gv.y + bv.y,
                      (v2-mean)*rstd*gv.z + bv.z, (v3-mean)*rstd*gv.w + bv.w};
  s16x4 hv, lv;
  #pragma unroll
  for (int e=0;e<4;e++){
    const short hb = f2b(v[e]);
    hv[e] = hb;
    lv[e] = f2b(v[e] - b2f(hb));
  }
  *(s16x4*)(Ohi + row*DM + tid*4) = hv;
  *(s16x4*)(Olo + row*DM + tid*4) = lv;
}

// ---------------- final projection + token embedding append ----------------
__global__ __launch_bounds__(256)
void out_step(const float* __restrict__ Dv, const float* __restrict__ outW,
              const float* __restrict__ outB, const float* __restrict__ tembW,
              const float* __restrict__ tembB, float* __restrict__ dout,
              float* __restrict__ tok, int s)
{
  const int b = blockIdx.x;
  const int tid = threadIdx.x;
  const float* drow = Dv + ((size_t)(b*NSTEP + s))*DM;
  const float4 dv = *(const float4*)(drow + tid*4);
  const float4 wv = *(const float4*)(outW + tid*4);
  float part = dv.x*wv.x + dv.y*wv.y + dv.z*wv.z + dv.w*wv.w;
  part = wave_sum(part);
  __shared__ float red[4];
  __shared__ float stepv;
  if ((tid&63)==0) red[tid>>6] = part;
  __syncthreads();
  if (tid==0) stepv = red[0]+red[1]+red[2]+red[3] + outB[0];
  __syncthreads();
  const float sv = stepv;
  if (tid==0) dout[b*NSTEP + s] = sv;
  if (s+1 < NSTEP) {
    const int d = tid*4;
    const float4 tw = *(const float4*)(tembW + d);
    const float4 tb = *(const float4*)(tembB + d);
    float4 e;
    e.x = fmaf(sv, tw.x, tb.x); e.y = fmaf(sv, tw.y, tb.y);
    e.z = fmaf(sv, tw.z, tb.z); e.w = fmaf(sv, tw.w, tb.w);
    *(float4*)(tok + ((size_t)(b*NSTEP + s + 1))*DM + d) = e;
  }
}

// ---------------- orchestration ----------------
extern "C" void kernel_launch(void* const* d_in, const int* in_sizes, int n_in,
                              void* d_out, int out_size, void* d_ws, size_t ws_size,
                              hipStream_t stream)
{
  (void)in_sizes; (void)n_in; (void)out_size; (void)ws_size;
  const float* x      = (const float*)d_in[0];
  const float* in_W   = (const float*)d_in[1];
  const float* in_b   = (const float*)d_in[2];
  const float* enc_Wq = (const float*)d_in[3];
  const float* enc_bq = (const float*)d_in[4];
  const float* enc_Wk = (const float*)d_in[5];
  const float* enc_bk = (const float*)d_in[6];
  const float* enc_Wv = (const float*)d_in[7];
  const float* enc_bv = (const float*)d_in[8];
  const float* enc_Wo = (const float*)d_in[9];
  const float* enc_bo = (const float*)d_in[10];
  const float* dec_Wq = (const float*)d_in[11];
  const float* dec_bq = (const float*)d_in[12];
  const float* dec_Wk = (const float*)d_in[13];
  const float* dec_bk = (const float*)d_in[14];
  const float* dec_Wv = (const float*)d_in[15];
  const float* dec_bv = (const float*)d_in[16];
  const float* dec_Wo = (const float*)d_in[17];
  const float* dec_bo = (const float*)d_in[18];
  const float* ffe_W1 = (const float*)d_in[19];
  const float* ffe_b1 = (const float*)d_in[20];
  const float* ffe_W2 = (const float*)d_in[21];
  const float* ffe_b2 = (const float*)d_in[22];
  const float* ffd_W1 = (const float*)d_in[23];
  const float* ffd_b1 = (const float*)d_in[24];
  const float* ffd_W2 = (const float*)d_in[25];
  const float* ffd_b2 = (const float*)d_in[26];
  const float* ne_g   = (const float*)d_in[27];
  const float* ne_b   = (const float*)d_in[28];
  const float* nd_g   = (const float*)d_in[29];
  const float* nd_b   = (const float*)d_in[30];
  const float* out_W  = (const float*)d_in[31];
  const float* out_b  = (const float*)d_in[32];
  const float* temb_W = (const float*)d_in[33];
  const float* temb_b = (const float*)d_in[34];
  float* dout = (float*)d_out;

  float* ws = (float*)d_ws;
  size_t off = 0;
  auto alloc  = [&](size_t n){ n = (n+3)&~(size_t)3; float* p = ws + off; off += n; return p; };
  auto allocS = [&](size_t n){ size_t nf = ((n+1)/2 + 3)&~(size_t)3; short* p = (short*)(ws + off); off += nf; return p; };

  // activations
  short* hshi = allocS((size_t)BT*DM);
  short* hslo = allocS((size_t)BT*DM);
  float* h    = alloc((size_t)BT*DM);          // input-proj out; aliased as hn
  float* hn   = h;
  float* t0   = alloc((size_t)BT*DM);          // QKV outs; aliased by fm split
  float* t1   = alloc((size_t)BT*DM);
  float* t2   = alloc((size_t)BT*DM);
  short* t3hi = allocS((size_t)BT*DM);
  short* t3lo = allocS((size_t)BT*DM);
  short* hnhi = allocS((size_t)BT*DM);
  short* hnlo = allocS((size_t)BT*DM);
  float* t4   = alloc((size_t)BT*DM);          // FFN2 out (encoder) UNION part (decoder)
  float* part = t4;
  short* fmhi = (short*)t0;                    // FFN hidden split: aliases t0..t3lo (16M floats)
  short* fmlo = fmhi + (size_t)BT*DFFN;
  // bf16 K/V cross-attn cache
  short* kcb  = allocS((size_t)NL*BT*DM);
  short* vcb  = allocS((size_t)NL*BT*DM);
  // split inputs (small, persistent)
  short* xshi = allocS((size_t)BT*64);
  short* xslo = allocS((size_t)BT*64);
  short* iwhi = allocS((size_t)DM*64);
  short* iwlo = allocS((size_t)DM*64);
  // per-layer reused weight slots (4x DM*DM hi+lo)
  short* w0hi = allocS((size_t)DM*DM); short* w0lo = allocS((size_t)DM*DM);
  short* w1hi = allocS((size_t)DM*DM); short* w1lo = allocS((size_t)DM*DM);
  short* w2hi = allocS((size_t)DM*DM); short* w2lo = allocS((size_t)DM*DM);
  short* w3hi = allocS((size_t)DM*DM); short* w3lo = allocS((size_t)DM*DM);
  // reused FFN weight slot (DFFN*DM hi+lo)
  short* wfhi = allocS((size_t)DFFN*DM); short* wflo = allocS((size_t)DFFN*DM);
  // decoder buffers
  float* tok  = alloc((size_t)MD*DM);
  float* dbuf = alloc((size_t)MD*DM);
  float* dq   = alloc((size_t)MD*DM);
  float* dk   = alloc((size_t)MD*DM);
  float* dv_  = alloc((size_t)MD*DM);
  float* dab  = alloc((size_t)MD*DM);
  float* dmid = alloc((size_t)MD*DFFN);
  float* dffo = alloc((size_t)MD*DM);
  float* opart= alloc((size_t)BB*NH*CSPLIT*NSTEP*DKH);
  float* mlp  = alloc((size_t)BB*NH*CSPLIT*2*NSTEP);

  auto cvt = [&](const float* src, short* hi, short* lo, size_t n){
    split_kernel<<<(int)((n/8 + 255)/256), 256, 0, stream>>>(src, hi, lo, (int)(n/8));
  };

  cvt(x,    xshi, xslo, (size_t)BT*64);
  cvt(in_W, iwhi, iwlo, (size_t)DM*64);
  zero_kernel<<<(MD*DM+255)/256, 256, 0, stream>>>(tok, MD*DM);

  // input projection + PE -> split
  gemm_split<0,0><<<dim3(BT/128, DM/128), 256, 0, stream>>>(
      xshi, xslo, iwhi, iwlo, in_b, h, (short*)nullptr, (short*)nullptr, BT, DM, 64);
  add_pe_split<<<BT, 256, 0, stream>>>(h, hshi, hslo);

  // ---- encoder ----
  for (int l=0; l<NL; ++l) {
    const size_t wo = (size_t)l*DM*DM, bo_ = (size_t)l*DM;
    cvt(enc_Wq+wo, w0hi, w0lo, (size_t)DM*DM);
    cvt(enc_Wk+wo, w1hi, w1lo, (size_t)DM*DM);
    cvt(enc_Wv+wo, w2hi, w2lo, (size_t)DM*DM);
    cvt(enc_Wo+wo, w3hi, w3lo, (size_t)DM*DM);
    gemm_split<0,0><<<dim3(32,8),256,0,stream>>>(hshi, hslo, w0hi, w0lo, enc_bq+bo_,
        t0, (short*)nullptr, (short*)nullptr, BT, DM, DM);
    gemm_split<0,0><<<dim3(32,8),256,0,stream>>>(hshi, hslo, w1hi, w1lo, enc_bk+bo_,
        t1, (short*)nullptr, (short*)nullptr, BT, DM, DM);
    gemm_split<0,0><<<dim3(32,8),256,0,stream>>>(hshi, hslo, w2hi, w2lo, enc_bv+bo_,
        t2, (short*)nullptr, (short*)nullptr, BT, DM, DM);
    attn_enc<<<dim3(TT/256, BB*NH),256,0,stream>>>(t0, t1, t2, t3hi, t3lo);
    gemm_split<0,2><<<dim3(32,8),256,0,stream>>>(t3hi, t3lo, w3hi, w3lo, enc_bo+bo_,
        hn, hnhi, hnlo, BT, DM, DM);
    cvt(ffe_W1, wfhi, wflo, (size_t)DFFN*DM);
    gemm_split<1,1><<<dim3(32,32),256,0,stream>>>(hnhi, hnlo, wfhi, wflo, ffe_b1,
        (float*)nullptr, fmhi, fmlo, BT, DFFN, DM);
    cvt(ffe_W2, wfhi, wflo, (size_t)DM*DFFN);
    gemm_split<0,0><<<dim3(32,8),256,0,stream>>>(fmhi, fmlo, wfhi, wflo, ffe_b2,
        t4, (short*)nullptr, (short*)nullptr, BT, DM, DFFN);
    ln_add_split<<<BT,256,0,stream>>>(hn, t4, ne_g, ne_b, hshi, hslo);
  }

  // ---- cross-attention K/V cache (bf16; h fixed after encoder, weights shared) ----
  for (int l=0; l<NL; ++l) {
    const size_t wo = (size_t)l*DM*DM, bo_ = (size_t)l*DM;
    cvt(dec_Wk+wo, w0hi, w0lo, (size_t)DM*DM);
    cvt(dec_Wv+wo, w1hi, w1lo, (size_t)DM*DM);
    gemm_split<0,3><<<dim3(32,8),256,0,stream>>>(hshi, hslo, w0hi, w0lo, dec_bk+bo_,
        (float*)nullptr, kcb+(size_t)l*BT*DM, (short*)nullptr, BT, DM, DM);
    gemm_split<0,3><<<dim3(32,8),256,0,stream>>>(hshi, hslo, w1hi, w1lo, dec_bv+bo_,
        (float*)nullptr, vcb+(size_t)l*BT*DM, (short*)nullptr, BT, DM, DM);
  }

  // ---- decoder (f32 path) ----
  for (int s=0; s<NSTEP; ++s) {
    const int n = s+1;
    dec_prep<<<MD,256,0,stream>>>(dbuf, tok);
    for (int l=0; l<NL; ++l) {
      const size_t wo = (size_t)l*DM*DM, bo_ = (size_t)l*DM;
      gemm_skinny<<<dim3(16,8,3),256,0,stream>>>(dbuf, dec_Wq+wo, dec_Wk+wo, dec_Wv+wo, part, DM, DM, 8);
      reduce_part<0><<<dim3(384,3),256,0,stream>>>(part, dec_bq+bo_, dec_bk+bo_, dec_bv+bo_, dq, dk, dv_, DM, 8);
      attn_dec_self<<<BB*NH,256,0,stream>>>(dq, dk, dv_, dab, n);
      gemm_skinny<<<dim3(16,8,1),256,0,stream>>>(dab, dec_Wo+wo, dec_Wo+wo, dec_Wo+wo, part, DM, DM, 8);
      reduce_part<0><<<dim3(384,1),256,0,stream>>>(part, dec_bo+bo_, dec_bo+bo_, dec_bo+bo_, dbuf, dbuf, dbuf, DM, 8);
      gemm_skinny<<<dim3(16,8,1),256,0,stream>>>(dbuf, dec_Wq+wo, dec_Wq+wo, dec_Wq+wo, part, DM, DM, 8);
      reduce_part<0><<<dim3(384,1),256,0,stream>>>(part, dec_bq+bo_, dec_bq+bo_, dec_bq+bo_, dq, dq, dq, DM, 8);
      attn_cross_part<<<dim3(CSPLIT, BB*NH),256,0,stream>>>(dq, kcb+(size_t)l*BT*DM, vcb+(size_t)l*BT*DM, opart, mlp);
      attn_cross_comb<<<dim3(BB*NH, 6),256,0,stream>>>(opart, mlp, dab);
      gemm_skinny<<<dim3(16,8,1),256,0,stream>>>(dab, dec_Wo+wo, dec_Wo+wo, dec_Wo+wo, part, DM, DM, 8);
      reduce_part<0><<<dim3(384,1),256,0,stream>>>(part, dec_bo+bo_, dec_bo+bo_, dec_bo+bo_, dbuf, dbuf, dbuf, DM, 8);
      gemm_skinny<<<dim3(64,8,1),256,0,stream>>>(dbuf, ffd_W1, ffd_W1, ffd_W1, part, DFFN, DM, 8);
      reduce_part<1><<<dim3(1536,1),256,0,stream>>>(part, ffd_b1, ffd_b1, ffd_b1, dmid, dmid, dmid, DFFN, 8);
      gemm_skinny<<<dim3(16,16,1),256,0,stream>>>(dmid, ffd_W2, ffd_W2, ffd_W2, part, DM, DFFN, 16);
      reduce_part<0><<<dim3(384,1),256,0,stream>>>(part, ffd_b2, ffd_b2, ffd_b2, dffo, dffo, dffo, DM, 16);
      ln_add<<<MD,256,0,stream>>>(dbuf, dffo, nd_g, nd_b, dbuf);
    }
    out_step<<<BB,256,0,stream>>>(dbuf, out_W, out_b, temb_W, temb_b, dout, tok, s);
  }
}

// Round 4
// 16500.465 us; speedup vs baseline: 1.6204x; 1.2301x over previous
//
#include <hip/hip_runtime.h>
#include <math.h>

#define DM    1024
#define NH    16
#define DKH   64
#define NL    4
#define DFFN  4096
#define BB    4
#define TT    1024
#define NSTEP 24
#define BT    (BB*TT)      // 4096 encoder rows
#define MD    (BB*NSTEP)   // 96 decoder rows max (packed: row = i*4 + b)
#define CSPLIT 8
#define CKEYS  (TT/CSPLIT) // 128 keys per cross-attn split

typedef __attribute__((ext_vector_type(8))) short s16x8;
typedef __attribute__((ext_vector_type(4))) short s16x4;
typedef __attribute__((ext_vector_type(4))) float f32x4;

__device__ inline short f2b(float f){
  unsigned u = __float_as_uint(f);
  u += 0x7fffu + ((u>>16)&1u);          // round-to-nearest-even
  return (short)(u>>16);
}
__device__ inline float b2f(short h){
  return __uint_as_float(((unsigned)(unsigned short)h)<<16);
}

// ---------------- f32 -> (hi,lo) bf16 split ----------------
__global__ __launch_bounds__(256)
void split_kernel(const float* __restrict__ X, short* __restrict__ Hi,
                  short* __restrict__ Lo, int n8)
{
  const size_t i = (size_t)blockIdx.x*256 + threadIdx.x;
  if (i >= (size_t)n8) return;
  const float4 v0 = *(const float4*)(X + i*8);
  const float4 v1 = *(const float4*)(X + i*8 + 4);
  const float f[8] = {v0.x,v0.y,v0.z,v0.w,v1.x,v1.y,v1.z,v1.w};
  s16x8 hv, lv;
  #pragma unroll
  for (int e=0;e<8;e++){
    const short h = f2b(f[e]);
    hv[e] = h;
    lv[e] = f2b(f[e] - b2f(h));
  }
  *(s16x8*)(Hi + i*8) = hv;
  *(s16x8*)(Lo + i*8) = lv;
}

__global__ void zero_kernel(float* __restrict__ p, int n) {
  int i = blockIdx.x*256 + threadIdx.x;
  if (i < n) p[i] = 0.f;
}

// h[row] + pe[row%TT] -> split bf16 (encoder)
__global__ __launch_bounds__(256)
void add_pe_split(const float* __restrict__ h, short* __restrict__ Hi,
                  short* __restrict__ Lo)
{
  const int row = blockIdx.x;
  const int pos = row & (TT-1);
  const int d = threadIdx.x*4;
  const float4 a = *(const float4*)(h + (size_t)row*DM + d);
  const float c1 = -9.210340371976184f / 1024.0f;
  const float e0 = expf((float)d * c1);
  const float e1 = expf((float)(d+2) * c1);
  const float a0 = (float)pos * e0, a1 = (float)pos * e1;
  const float v[4] = {a.x + sinf(a0), a.y + cosf(a0), a.z + sinf(a1), a.w + cosf(a1)};
  s16x4 hv, lv;
  #pragma unroll
  for (int e=0;e<4;e++){
    const short hb = f2b(v[e]);
    hv[e] = hb;
    lv[e] = f2b(v[e] - b2f(hb));
  }
  *(s16x4*)(Hi + (size_t)row*DM + d) = hv;
  *(s16x4*)(Lo + (size_t)row*DM + d) = lv;
}

// decoder: dbuf_split[r] = tok[r] + pe[i], packed row r = i*4+b, grid = 4n rows
__global__ __launch_bounds__(256)
void dec_prep_split(short* __restrict__ Dhi, short* __restrict__ Dlo,
                    const float* __restrict__ tok)
{
  const int r = blockIdx.x;
  const int i = r >> 2;                 // position
  const int d = threadIdx.x*4;
  const float4 a = *(const float4*)(tok + (size_t)r*DM + d);
  const float c1 = -9.210340371976184f / 1024.0f;
  const float e0 = expf((float)d * c1);
  const float e1 = expf((float)(d+2) * c1);
  const float a0 = (float)i * e0, a1 = (float)i * e1;
  const float v[4] = {a.x + sinf(a0), a.y + cosf(a0), a.z + sinf(a1), a.w + cosf(a1)};
  s16x4 hv, lv;
  #pragma unroll
  for (int e=0;e<4;e++){
    const short hb = f2b(v[e]);
    hv[e] = hb;
    lv[e] = f2b(v[e] - b2f(hb));
  }
  *(s16x4*)(Dhi + (size_t)r*DM + d) = hv;
  *(s16x4*)(Dlo + (size_t)r*DM + d) = lv;
}

// ---------------- split-bf16 MFMA GEMM (encoder): C = A @ W^T + bias ----------
// OUT_MODE: 0 = f32 C; 1 = split (Chi,Clo); 2 = both; 3 = plain-bf16 Chi only.
template<int ACT, int OUT_MODE>
__global__ __launch_bounds__(256, 2)
void gemm_split(const short* __restrict__ Ahi, const short* __restrict__ Alo,
                const short* __restrict__ Bhi, const short* __restrict__ Blo,
                const float* __restrict__ bias,
                float* __restrict__ C, short* __restrict__ Chi, short* __restrict__ Clo,
                int M, int N, int K)
{
  __shared__ __align__(16) short lA[2][128][40];   // [hi/lo][row][k], 80B row stride
  __shared__ __align__(16) short lB[2][128][40];
  const int tid = threadIdx.x;
  const int m0 = blockIdx.x*128, n0 = blockIdx.y*128;
  const int lane = tid & 63, w = tid >> 6;
  const int wr = w >> 1, wc = w & 1;           // wave quadrant (64x64)
  const int fr = lane & 15, fq = lane >> 4;    // frag row/col, k-quarter

  f32x4 acc[4][4];
  #pragma unroll
  for (int i=0;i<4;i++)
    #pragma unroll
    for (int j=0;j<4;j++) acc[i][j] = (f32x4){0.f,0.f,0.f,0.f};

  for (int k0 = 0; k0 < K; k0 += 32) {
    __syncthreads();
    #pragma unroll
    for (int j=0;j<2;j++){
      const int cc = tid + j*256;              // 0..511
      const int row = cc >> 2, kq = cc & 3;
      const size_t ga = (size_t)(m0+row)*K + k0 + kq*8;
      const size_t gb = (size_t)(n0+row)*K + k0 + kq*8;
      *(s16x8*)&lA[0][row][kq*8] = *(const s16x8*)(Ahi + ga);
      *(s16x8*)&lA[1][row][kq*8] = *(const s16x8*)(Alo + ga);
      *(s16x8*)&lB[0][row][kq*8] = *(const s16x8*)(Bhi + gb);
      *(s16x8*)&lB[1][row][kq*8] = *(const s16x8*)(Blo + gb);
    }
    __syncthreads();
    s16x8 ah[4], al[4], bh[4], bl[4];
    #pragma unroll
    for (int i=0;i<4;i++){
      ah[i] = *(const s16x8*)&lA[0][wr*64+i*16+fr][fq*8];
      al[i] = *(const s16x8*)&lA[1][wr*64+i*16+fr][fq*8];
    }
    #pragma unroll
    for (int j=0;j<4;j++){
      bh[j] = *(const s16x8*)&lB[0][wc*64+j*16+fr][fq*8];
      bl[j] = *(const s16x8*)&lB[1][wc*64+j*16+fr][fq*8];
    }
    #pragma unroll
    for (int i=0;i<4;i++)
      #pragma unroll
      for (int j=0;j<4;j++){
        acc[i][j] = __builtin_amdgcn_mfma_f32_16x16x32_bf16(ah[i], bh[j], acc[i][j], 0,0,0);
        acc[i][j] = __builtin_amdgcn_mfma_f32_16x16x32_bf16(ah[i], bl[j], acc[i][j], 0,0,0);
        acc[i][j] = __builtin_amdgcn_mfma_f32_16x16x32_bf16(al[i], bh[j], acc[i][j], 0,0,0);
      }
  }
  // epilogue: C/D layout col=lane&15, row=(lane>>4)*4+reg  [verified m89]
  #pragma unroll
  for (int j=0;j<4;j++){
    const int col = n0 + wc*64 + j*16 + fr;
    const float bv = bias[col];
    #pragma unroll
    for (int i=0;i<4;i++){
      const int row0 = m0 + wr*64 + i*16 + fq*4;
      #pragma unroll
      for (int r=0;r<4;r++){
        float v = acc[i][j][r] + bv;
        if (ACT==1) v = fmaxf(v, 0.f);
        const size_t idx = (size_t)(row0+r)*N + col;
        if (OUT_MODE==0 || OUT_MODE==2) C[idx] = v;
        if (OUT_MODE==1 || OUT_MODE==2){
          const short hb = f2b(v);
          Chi[idx] = hb;
          Clo[idx] = f2b(v - b2f(hb));
        }
        if (OUT_MODE==3) Chi[idx] = f2b(v);
      }
    }
  }
}

// ---------------- decoder split-bf16 MFMA GEMM (small M, K-split partials) ------
// A[Mt x K] split bf16 (packed rows), W[N x K] split bf16 (3 selectable),
// partials P[z][ks][96][N] f32. Tile: Mt x 128, 4 waves (32 cols each).
template<int MR>
__global__ __launch_bounds__(256)
void gemm_dec(const short* __restrict__ Ahi, const short* __restrict__ Alo,
              const short* __restrict__ B0hi, const short* __restrict__ B0lo,
              const short* __restrict__ B1hi, const short* __restrict__ B1lo,
              const short* __restrict__ B2hi, const short* __restrict__ B2lo,
              float* __restrict__ part, int N, int K, int KS)
{
  const short* Bhi = (blockIdx.z==0) ? B0hi : (blockIdx.z==1 ? B1hi : B2hi);
  const short* Blo = (blockIdx.z==0) ? B0lo : (blockIdx.z==1 ? B1lo : B2lo);
  float* P = part + ((size_t)blockIdx.z*KS + blockIdx.y)*(size_t)MD*N;
  const int KK = K / KS;
  const int kbase = blockIdx.y * KK;
  const int n0 = blockIdx.x * 128;
  __shared__ __align__(16) short lA[2][96][40];
  __shared__ __align__(16) short lB[2][128][40];
  const int tid = threadIdx.x;
  const int lane = tid & 63, w = tid >> 6;
  const int fr = lane & 15, fq = lane >> 4;
  constexpr int CH = MR*128;                 // A staging chunks (Mt rows x 8)

  f32x4 acc[MR][2];
  #pragma unroll
  for (int i=0;i<MR;i++){ acc[i][0]=(f32x4){0,0,0,0}; acc[i][1]=(f32x4){0,0,0,0}; }

  for (int k0 = kbase; k0 < kbase + KK; k0 += 32) {
    __syncthreads();
    #pragma unroll
    for (int t=0; t<(CH+255)/256; t++){
      const int cc = tid + t*256;
      if (cc < CH){
        const int row = cc>>3, hl = (cc>>2)&1, kq = cc&3;
        const short* src = hl ? Alo : Ahi;
        *(s16x8*)&lA[hl][row][kq*8] = *(const s16x8*)(src + (size_t)row*K + k0 + kq*8);
      }
    }
    #pragma unroll
    for (int t=0; t<4; t++){
      const int cc = tid + t*256;
      const int row = cc>>3, hl = (cc>>2)&1, kq = cc&3;
      const short* src = hl ? Blo : Bhi;
      *(s16x8*)&lB[hl][row][kq*8] = *(const s16x8*)(src + (size_t)(n0+row)*K + k0 + kq*8);
    }
    __syncthreads();
    s16x8 bh[2], bl[2];
    #pragma unroll
    for (int j=0;j<2;j++){
      bh[j] = *(const s16x8*)&lB[0][w*32+j*16+fr][fq*8];
      bl[j] = *(const s16x8*)&lB[1][w*32+j*16+fr][fq*8];
    }
    #pragma unroll
    for (int i=0;i<MR;i++){
      const s16x8 ah = *(const s16x8*)&lA[0][i*16+fr][fq*8];
      const s16x8 al = *(const s16x8*)&lA[1][i*16+fr][fq*8];
      #pragma unroll
      for (int j=0;j<2;j++){
        acc[i][j] = __builtin_amdgcn_mfma_f32_16x16x32_bf16(ah, bh[j], acc[i][j], 0,0,0);
        acc[i][j] = __builtin_amdgcn_mfma_f32_16x16x32_bf16(ah, bl[j], acc[i][j], 0,0,0);
        acc[i][j] = __builtin_amdgcn_mfma_f32_16x16x32_bf16(al, bh[j], acc[i][j], 0,0,0);
      }
    }
  }
  #pragma unroll
  for (int j=0;j<2;j++){
    const int col = n0 + w*32 + j*16 + fr;
    #pragma unroll
    for (int i=0;i<MR;i++){
      const int row0 = i*16 + fq*4;
      #pragma unroll
      for (int r=0;r<4;r++)
        P[(size_t)(row0+r)*N + col] = acc[i][j][r];
    }
  }
}

// reduce partials + bias (+ReLU); MODE: 0=f32, 1=split, 2=both (split for z==0 only)
template<int ACT, int MODE>
__global__ __launch_bounds__(256)
void reduce_dec(const float* __restrict__ part,
                const float* __restrict__ b0, const float* __restrict__ b1,
                const float* __restrict__ b2,
                float* __restrict__ o0, float* __restrict__ o1, float* __restrict__ o2,
                short* __restrict__ ohi, short* __restrict__ olo,
                int N, int KS)
{
  const int idx = blockIdx.x*256 + threadIdx.x;
  const int z = blockIdx.y;
  const float* P = part + (size_t)z*KS*(size_t)MD*N;
  const float* bias = (z==0)?b0:(z==1?b1:b2);
  float* out = (z==0)?o0:(z==1?o1:o2);
  float s = 0.f;
  for (int ks=0; ks<KS; ks++) s += P[(size_t)ks*MD*N + idx];
  s += bias[idx & (N-1)];
  if (ACT==1) s = fmaxf(s, 0.f);
  if (MODE==0 || MODE==2) out[idx] = s;
  if (MODE==1 || MODE==2){
    if (z==0){
      const short hb = f2b(s);
      ohi[idx] = hb;
      olo[idx] = f2b(s - b2f(hb));
    }
  }
}

// ---------------- encoder self-attention (flash, thread-per-q-row, split out) ----
__global__ __launch_bounds__(256)
void attn_enc(const float* __restrict__ Qg, const float* __restrict__ Kg,
              const float* __restrict__ Vg, short* __restrict__ Ohi,
              short* __restrict__ Olo)
{
  const int bh = blockIdx.y;
  const int b = bh >> 4, hh = bh & 15;
  const int row = blockIdx.x*256 + threadIdx.x;
  const size_t base = ((size_t)b*TT)*DM + hh*DKH;
  float q[64];
  {
    const float* qp = Qg + base + (size_t)row*DM;
    #pragma unroll
    for (int d4=0; d4<16; d4++){
      const float4 v = *(const float4*)(qp + d4*4);
      q[d4*4+0]=v.x; q[d4*4+1]=v.y; q[d4*4+2]=v.z; q[d4*4+3]=v.w;
    }
  }
  float o[64];
  #pragma unroll
  for (int d=0;d<64;d++) o[d]=0.f;
  float m = -INFINITY, l = 0.f;
  __shared__ float Ks[64][68];
  __shared__ float Vs[64][68];
  for (int kt=0; kt<TT; kt+=64) {
    __syncthreads();
    #pragma unroll
    for (int t=0;t<4;t++){
      const int fi = threadIdx.x + t*256;
      const int j = fi>>4, dq = fi&15;
      *(float4*)&Ks[j][dq*4] = *(const float4*)(Kg + base + (size_t)(kt+j)*DM + dq*4);
      *(float4*)&Vs[j][dq*4] = *(const float4*)(Vg + base + (size_t)(kt+j)*DM + dq*4);
    }
    __syncthreads();
    for (int j=0;j<64;j++){
      float s0=0.f,s1=0.f,s2=0.f,s3=0.f;
      #pragma unroll
      for (int d=0; d<64; d+=4){
        s0 = fmaf(q[d+0], Ks[j][d+0], s0);
        s1 = fmaf(q[d+1], Ks[j][d+1], s1);
        s2 = fmaf(q[d+2], Ks[j][d+2], s2);
        s3 = fmaf(q[d+3], Ks[j][d+3], s3);
      }
      const float s = ((s0+s1)+(s2+s3)) * 0.125f;
      if (s > m) {
        const float f = __expf(m - s);
        l *= f;
        #pragma unroll
        for (int d=0;d<64;d++) o[d] *= f;
        m = s;
      }
      const float p = __expf(s - m);
      l += p;
      #pragma unroll
      for (int d=0;d<64;d++) o[d] = fmaf(p, Vs[j][d], o[d]);
    }
  }
  const float inv = 1.f / l;
  #pragma unroll
  for (int d8=0; d8<8; d8++){
    s16x8 hv, lv;
    #pragma unroll
    for (int e=0;e<8;e++){
      const float f = o[d8*8+e]*inv;
      const short hb = f2b(f);
      hv[e] = hb;
      lv[e] = f2b(f - b2f(hb));
    }
    *(s16x8*)(Ohi + base + (size_t)row*DM + d8*8) = hv;
    *(s16x8*)(Olo + base + (size_t)row*DM + d8*8) = lv;
  }
}

// ---------------- decoder self-attention (packed rows, split out) ----------------
__global__ __launch_bounds__(256)
void attn_dec_selfp(const float* __restrict__ Qg, const float* __restrict__ Kg,
                    const float* __restrict__ Vg, short* __restrict__ Ohi,
                    short* __restrict__ Olo, int n)
{
  const int b = blockIdx.x >> 4, hh = blockIdx.x & 15;
  const size_t base = (size_t)b*DM + hh*DKH;      // + (i*4)*DM per position
  __shared__ float Qs[NSTEP][68], Ks[NSTEP][68], Vs[NSTEP][68];
  __shared__ float P[NSTEP][28];
  const int tid = threadIdx.x;
  for (int t = tid; t < 3*n*16; t += 256) {
    const int tensor = t / (n*16);
    const int fi = t - tensor*(n*16);
    const int row = fi >> 4, dq = fi & 15;
    const float* src = (tensor==0?Qg:(tensor==1?Kg:Vg)) + base + (size_t)(row*4)*DM + dq*4;
    float (*dst)[68] = (tensor==0?Qs:(tensor==1?Ks:Vs));
    *(float4*)&dst[row][dq*4] = *(const float4*)src;
  }
  __syncthreads();
  for (int idx = tid; idx < n*n; idx += 256) {
    const int i = idx / n, j = idx - i*n;
    float s0=0.f,s1=0.f,s2=0.f,s3=0.f;
    #pragma unroll
    for (int d=0; d<64; d+=4){
      s0 = fmaf(Qs[i][d+0], Ks[j][d+0], s0);
      s1 = fmaf(Qs[i][d+1], Ks[j][d+1], s1);
      s2 = fmaf(Qs[i][d+2], Ks[j][d+2], s2);
      s3 = fmaf(Qs[i][d+3], Ks[j][d+3], s3);
    }
    P[i][j] = ((s0+s1)+(s2+s3))*0.125f;
  }
  __syncthreads();
  if (tid < n) {
    float mm = -INFINITY;
    for (int j=0;j<n;j++) mm = fmaxf(mm, P[tid][j]);
    float l = 0.f;
    for (int j=0;j<n;j++){ const float p = __expf(P[tid][j]-mm); P[tid][j]=p; l+=p; }
    const float inv = 1.f/l;
    for (int j=0;j<n;j++) P[tid][j] *= inv;
  }
  __syncthreads();
  for (int idx = tid; idx < n*64; idx += 256){
    const int i = idx >> 6, d = idx & 63;
    float s = 0.f;
    for (int j=0;j<n;j++) s = fmaf(P[i][j], Vs[j][d], s);
    const short hb = f2b(s);
    const size_t o = base + (size_t)(i*4)*DM + d;
    Ohi[o] = hb;
    Olo[o] = f2b(s - b2f(hb));
  }
}

// ---------------- decoder cross-attention (bf16 K/V cache): split-K + combine -----
__global__ __launch_bounds__(256)
void attn_cross_part(const float* __restrict__ Qg, const short* __restrict__ Kc,
                     const short* __restrict__ Vc, float* __restrict__ opart,
                     float* __restrict__ mlpart, int n)
{
  const int ks = blockIdx.x;
  const int bh = blockIdx.y;
  const int b = bh >> 4, hh = bh & 15;
  __shared__ float Qs[NSTEP][68];
  __shared__ float KVs[CKEYS][68];        // K first, then reused for V
  __shared__ float S[NSTEP][CKEYS+4];
  const int tid = threadIdx.x;
  const size_t qbase = (size_t)b*DM + hh*DKH;
  for (int t=tid; t<n*16; t+=256){
    const int row = t>>4, dq = t&15;
    *(float4*)&Qs[row][dq*4] = *(const float4*)(Qg + qbase + (size_t)(row*4)*DM + dq*4);
  }
  const size_t kbase = ((size_t)b*TT + (size_t)ks*CKEYS)*DM + hh*DKH;
  for (int t=tid; t<CKEYS*8; t+=256){
    const int row = t>>3, d8 = t&7;
    const s16x8 v = *(const s16x8*)(Kc + kbase + (size_t)row*DM + d8*8);
    #pragma unroll
    for (int e=0;e<8;e++) KVs[row][d8*8+e] = b2f(v[e]);
  }
  __syncthreads();
  for (int idx=tid; idx<n*128; idx+=256){
    const int i = idx >> 7, j = idx & 127;
    float s0=0.f,s1=0.f,s2=0.f,s3=0.f;
    #pragma unroll
    for (int d=0; d<64; d+=4){
      s0 = fmaf(Qs[i][d+0], KVs[j][d+0], s0);
      s1 = fmaf(Qs[i][d+1], KVs[j][d+1], s1);
      s2 = fmaf(Qs[i][d+2], KVs[j][d+2], s2);
      s3 = fmaf(Qs[i][d+3], KVs[j][d+3], s3);
    }
    S[i][j] = ((s0+s1)+(s2+s3))*0.125f;
  }
  __syncthreads();
  // stage V over the K buffer while n threads do softmax
  for (int t=tid; t<CKEYS*8; t+=256){
    const int row = t>>3, d8 = t&7;
    const s16x8 v = *(const s16x8*)(Vc + kbase + (size_t)row*DM + d8*8);
    #pragma unroll
    for (int e=0;e<8;e++) KVs[row][d8*8+e] = b2f(v[e]);
  }
  if (tid < n){
    float mm=-INFINITY;
    for (int j=0;j<CKEYS;j++) mm = fmaxf(mm, S[tid][j]);
    float l=0.f;
    for (int j=0;j<CKEYS;j++){ const float p=__expf(S[tid][j]-mm); S[tid][j]=p; l+=p; }
    mlpart[((size_t)bh*CSPLIT+ks)*(2*NSTEP) + tid*2+0] = mm;
    mlpart[((size_t)bh*CSPLIT+ks)*(2*NSTEP) + tid*2+1] = l;
  }
  __syncthreads();
  for (int idx=tid; idx<n*64; idx+=256){
    const int i = idx >> 6, d = idx & 63;
    float s=0.f;
    for (int j=0;j<CKEYS;j++) s = fmaf(S[i][j], KVs[j][d], s);
    opart[(((size_t)bh*CSPLIT+ks)*NSTEP + i)*DKH + d] = s;
  }
}

__global__ __launch_bounds__(256)
void attn_cross_comb(const float* __restrict__ opart, const float* __restrict__ mlpart,
                     short* __restrict__ Ohi, short* __restrict__ Olo, int n)
{
  const int bh = blockIdx.x;
  const int idx = blockIdx.y*256 + threadIdx.x;
  const int i = idx >> 6, d = idx & 63;
  if (i >= n) return;
  float M = -INFINITY;
  #pragma unroll
  for (int s=0;s<CSPLIT;s++)
    M = fmaxf(M, mlpart[((size_t)bh*CSPLIT+s)*(2*NSTEP) + i*2]);
  float acc = 0.f, L = 0.f;
  #pragma unroll
  for (int s=0;s<CSPLIT;s++){
    const float mm = mlpart[((size_t)bh*CSPLIT+s)*(2*NSTEP) + i*2+0];
    const float ll = mlpart[((size_t)bh*CSPLIT+s)*(2*NSTEP) + i*2+1];
    const float f = __expf(mm - M);
    acc = fmaf(f, opart[(((size_t)bh*CSPLIT+s)*NSTEP + i)*DKH + d], acc);
    L   = fmaf(f, ll, L);
  }
  const int b = bh >> 4, hh = bh & 15;
  const float v = acc / L;
  const short hb = f2b(v);
  const size_t o = ((size_t)(i*4+b))*DM + hh*DKH + d;
  Ohi[o] = hb;
  Olo[o] = f2b(v - b2f(hb));
}

// ---------------- LayerNorm ----------------
__device__ inline float wave_sum(float v){
  #pragma unroll
  for (int off=1; off<64; off<<=1) v += __shfl_xor(v, off, 64);
  return v;
}

// encoder version: split bf16 out
__global__ __launch_bounds__(256)
void ln_add_split(const float* __restrict__ X, const float* __restrict__ Y,
                  const float* __restrict__ g, const float* __restrict__ be,
                  short* __restrict__ Ohi, short* __restrict__ Olo)
{
  const size_t row = blockIdx.x;
  const int tid = threadIdx.x;
  const float4 a = *(const float4*)(X + row*DM + tid*4);
  const float4 b = *(const float4*)(Y + row*DM + tid*4);
  const float v0=a.x+b.x, v1=a.y+b.y, v2=a.z+b.z, v3=a.w+b.w;
  float s = v0+v1+v2+v3;
  float q = v0*v0+v1*v1+v2*v2+v3*v3;
  s = wave_sum(s); q = wave_sum(q);
  __shared__ float rs[4], rq[4];
  if ((tid&63)==0){ rs[tid>>6]=s; rq[tid>>6]=q; }
  __syncthreads();
  const float S = rs[0]+rs[1]+rs[2]+rs[3];
  const float Q = rq[0]+rq[1]+rq[2]+rq[3];
  const float mean = S * (1.f/DM);
  const float var  = Q * (1.f/DM) - mean*mean;
  const float rstd = rsqrtf(var + 1e-5f);
  const float4 gv = *(const float4*)(g  + tid*4);
  const float4 bv = *(const float4*)(be + tid*4);
  const float v[4] = {(v0-mean)*rstd*gv.x + bv.x, (v1-mean)*rstd*gv.y + bv.y,
                      (v2-mean)*rstd*gv.z + bv.z, (v3-mean)*rstd*gv.w + bv.w};
  s16x4 hv, lv;
  #pragma unroll
  for (int e=0;e<4;e++){
    const short hb = f2b(v[e]);
    hv[e] = hb;
    lv[e] = f2b(v[e] - b2f(hb));
  }
  *(s16x4*)(Ohi + row*DM + tid*4) = hv;
  *(s16x4*)(Olo + row*DM + tid*4) = lv;
}

// decoder version: f32 out + split out
__global__ __launch_bounds__(256)
void ln_add_dec(const float* __restrict__ X, const float* __restrict__ Y,
                const float* __restrict__ g, const float* __restrict__ be,
                float* __restrict__ Outf, short* __restrict__ Ohi,
                short* __restrict__ Olo)
{
  const size_t row = blockIdx.x;
  const int tid = threadIdx.x;
  const float4 a = *(const float4*)(X + row*DM + tid*4);
  const float4 b = *(const float4*)(Y + row*DM + tid*4);
  const float v0=a.x+b.x, v1=a.y+b.y, v2=a.z+b.z, v3=a.w+b.w;
  float s = v0+v1+v2+v3;
  float q = v0*v0+v1*v1+v2*v2+v3*v3;
  s = wave_sum(s); q = wave_sum(q);
  __shared__ float rs[4], rq[4];
  if ((tid&63)==0){ rs[tid>>6]=s; rq[tid>>6]=q; }
  __syncthreads();
  const float S = rs[0]+rs[1]+rs[2]+rs[3];
  const float Q = rq[0]+rq[1]+rq[2]+rq[3];
  const float mean = S * (1.f/DM);
  const float var  = Q * (1.f/DM) - mean*mean;
  const float rstd = rsqrtf(var + 1e-5f);
  const float4 gv = *(const float4*)(g  + tid*4);
  const float4 bv = *(const float4*)(be + tid*4);
  const float v[4] = {(v0-mean)*rstd*gv.x + bv.x, (v1-mean)*rstd*gv.y + bv.y,
                      (v2-mean)*rstd*gv.z + bv.z, (v3-mean)*rstd*gv.w + bv.w};
  float4 of; of.x=v[0]; of.y=v[1]; of.z=v[2]; of.w=v[3];
  *(float4*)(Outf + row*DM + tid*4) = of;
  s16x4 hv, lv;
  #pragma unroll
  for (int e=0;e<4;e++){
    const short hb = f2b(v[e]);
    hv[e] = hb;
    lv[e] = f2b(v[e] - b2f(hb));
  }
  *(s16x4*)(Ohi + row*DM + tid*4) = hv;
  *(s16x4*)(Olo + row*DM + tid*4) = lv;
}

// ---------------- final projection + token embedding append (packed rows) --------
__global__ __launch_bounds__(256)
void out_step(const float* __restrict__ Dv, const float* __restrict__ outW,
              const float* __restrict__ outB, const float* __restrict__ tembW,
              const float* __restrict__ tembB, float* __restrict__ dout,
              float* __restrict__ tok, int s)
{
  const int b = blockIdx.x;
  const int tid = threadIdx.x;
  const float* drow = Dv + ((size_t)(s*4 + b))*DM;
  const float4 dv = *(const float4*)(drow + tid*4);
  const float4 wv = *(const float4*)(outW + tid*4);
  float part = dv.x*wv.x + dv.y*wv.y + dv.z*wv.z + dv.w*wv.w;
  part = wave_sum(part);
  __shared__ float red[4];
  __shared__ float stepv;
  if ((tid&63)==0) red[tid>>6] = part;
  __syncthreads();
  if (tid==0) stepv = red[0]+red[1]+red[2]+red[3] + outB[0];
  __syncthreads();
  const float sv = stepv;
  if (tid==0) dout[b*NSTEP + s] = sv;
  if (s+1 < NSTEP) {
    const int d = tid*4;
    const float4 tw = *(const float4*)(tembW + d);
    const float4 tb = *(const float4*)(tembB + d);
    float4 e;
    e.x = fmaf(sv, tw.x, tb.x); e.y = fmaf(sv, tw.y, tb.y);
    e.z = fmaf(sv, tw.z, tb.z); e.w = fmaf(sv, tw.w, tb.w);
    *(float4*)(tok + ((size_t)((s+1)*4 + b))*DM + d) = e;
  }
}

// ---------------- orchestration ----------------
extern "C" void kernel_launch(void* const* d_in, const int* in_sizes, int n_in,
                              void* d_out, int out_size, void* d_ws, size_t ws_size,
                              hipStream_t stream)
{
  (void)in_sizes; (void)n_in; (void)out_size; (void)ws_size;
  const float* x      = (const float*)d_in[0];
  const float* in_W   = (const float*)d_in[1];
  const float* in_b   = (const float*)d_in[2];
  const float* enc_Wq = (const float*)d_in[3];
  const float* enc_bq = (const float*)d_in[4];
  const float* enc_Wk = (const float*)d_in[5];
  const float* enc_bk = (const float*)d_in[6];
  const float* enc_Wv = (const float*)d_in[7];
  const float* enc_bv = (const float*)d_in[8];
  const float* enc_Wo = (const float*)d_in[9];
  const float* enc_bo = (const float*)d_in[10];
  const float* dec_Wq = (const float*)d_in[11];
  const float* dec_bq = (const float*)d_in[12];
  const float* dec_Wk = (const float*)d_in[13];
  const float* dec_bk = (const float*)d_in[14];
  const float* dec_Wv = (const float*)d_in[15];
  const float* dec_bv = (const float*)d_in[16];
  const float* dec_Wo = (const float*)d_in[17];
  const float* dec_bo = (const float*)d_in[18];
  const float* ffe_W1 = (const float*)d_in[19];
  const float* ffe_b1 = (const float*)d_in[20];
  const float* ffe_W2 = (const float*)d_in[21];
  const float* ffe_b2 = (const float*)d_in[22];
  const float* ffd_W1 = (const float*)d_in[23];
  const float* ffd_b1 = (const float*)d_in[24];
  const float* ffd_W2 = (const float*)d_in[25];
  const float* ffd_b2 = (const float*)d_in[26];
  const float* ne_g   = (const float*)d_in[27];
  const float* ne_b   = (const float*)d_in[28];
  const float* nd_g   = (const float*)d_in[29];
  const float* nd_b   = (const float*)d_in[30];
  const float* out_W  = (const float*)d_in[31];
  const float* out_b  = (const float*)d_in[32];
  const float* temb_W = (const float*)d_in[33];
  const float* temb_b = (const float*)d_in[34];
  float* dout = (float*)d_out;

  float* ws = (float*)d_ws;
  size_t off = 0;
  auto alloc  = [&](size_t n){ n = (n+3)&~(size_t)3; float* p = ws + off; off += n; return p; };
  auto allocS = [&](size_t n){ size_t nf = ((n+1)/2 + 3)&~(size_t)3; short* p = (short*)(ws + off); off += nf; return p; };

  // activations (encoder)
  short* hshi = allocS((size_t)BT*DM);
  short* hslo = allocS((size_t)BT*DM);
  float* h    = alloc((size_t)BT*DM);          // input-proj out; aliased as hn
  float* hn   = h;
  float* t0   = alloc((size_t)BT*DM);          // QKV outs; aliased by fm split
  float* t1   = alloc((size_t)BT*DM);
  float* t2   = alloc((size_t)BT*DM);
  short* t3hi = allocS((size_t)BT*DM);
  short* t3lo = allocS((size_t)BT*DM);
  short* hnhi = allocS((size_t)BT*DM);
  short* hnlo = allocS((size_t)BT*DM);
  float* t4   = alloc((size_t)BT*DM);          // FFN2 out (encoder) UNION part (decoder)
  float* part = t4;
  short* fmhi = (short*)t0;                    // FFN hidden split: aliases t0..t3lo
  short* fmlo = fmhi + (size_t)BT*DFFN;
  // bf16 K/V cross-attn cache
  short* kcb  = allocS((size_t)NL*BT*DM);
  short* vcb  = allocS((size_t)NL*BT*DM);
  // split inputs (small, persistent)
  short* xshi = allocS((size_t)BT*64);
  short* xslo = allocS((size_t)BT*64);
  short* iwhi = allocS((size_t)DM*64);
  short* iwlo = allocS((size_t)DM*64);
  // per-layer reused weight slots (encoder + KV build)
  short* w0hi = allocS((size_t)DM*DM); short* w0lo = allocS((size_t)DM*DM);
  short* w1hi = allocS((size_t)DM*DM); short* w1lo = allocS((size_t)DM*DM);
  short* w2hi = allocS((size_t)DM*DM); short* w2lo = allocS((size_t)DM*DM);
  short* w3hi = allocS((size_t)DM*DM); short* w3lo = allocS((size_t)DM*DM);
  short* wfhi = allocS((size_t)DFFN*DM); short* wflo = allocS((size_t)DFFN*DM);
  // decoder buffers (packed rows r = i*4+b)
  float* tok  = alloc((size_t)MD*DM);
  float* dbuf = alloc((size_t)MD*DM);
  float* dq   = alloc((size_t)MD*DM);
  float* dk   = alloc((size_t)MD*DM);
  float* dv_  = alloc((size_t)MD*DM);
  float* dffo = alloc((size_t)MD*DM);
  short* dbhi = allocS((size_t)MD*DM);  short* dblo = allocS((size_t)MD*DM);
  short* dahi = allocS((size_t)MD*DM);  short* dalo = allocS((size_t)MD*DM);
  short* dmhi = allocS((size_t)MD*DFFN);short* dmlo = allocS((size_t)MD*DFFN);
  float* opart= alloc((size_t)BB*NH*CSPLIT*NSTEP*DKH);
  float* mlp  = alloc((size_t)BB*NH*CSPLIT*2*NSTEP);

  // decoder split weights aliased onto dead-after-encoder buffers
  const size_t MM = (size_t)DM*DM;
  short* dwq = (short*)t0;      // 4 layers x (hi MM | lo MM) = 16 MB
  short* dwk = (short*)t1;
  short* dwv = (short*)t2;
  short* dwo = (short*)h;
  short* fw1h = t3hi; short* fw1l = t3lo;      // DFFN*DM each
  short* fw2h = hnhi; short* fw2l = hnlo;

  auto cvt = [&](const float* src, short* hi, short* lo, size_t n){
    split_kernel<<<(int)((n/8 + 255)/256), 256, 0, stream>>>(src, hi, lo, (int)(n/8));
  };

  cvt(x,    xshi, xslo, (size_t)BT*64);
  cvt(in_W, iwhi, iwlo, (size_t)DM*64);
  zero_kernel<<<(MD*DM+255)/256, 256, 0, stream>>>(tok, MD*DM);

  // input projection + PE -> split
  gemm_split<0,0><<<dim3(BT/128, DM/128), 256, 0, stream>>>(
      xshi, xslo, iwhi, iwlo, in_b, h, (short*)nullptr, (short*)nullptr, BT, DM, 64);
  add_pe_split<<<BT, 256, 0, stream>>>(h, hshi, hslo);

  // ---- encoder ----
  for (int l=0; l<NL; ++l) {
    const size_t wo = (size_t)l*DM*DM, bo_ = (size_t)l*DM;
    cvt(enc_Wq+wo, w0hi, w0lo, MM);
    cvt(enc_Wk+wo, w1hi, w1lo, MM);
    cvt(enc_Wv+wo, w2hi, w2lo, MM);
    cvt(enc_Wo+wo, w3hi, w3lo, MM);
    gemm_split<0,0><<<dim3(32,8),256,0,stream>>>(hshi, hslo, w0hi, w0lo, enc_bq+bo_,
        t0, (short*)nullptr, (short*)nullptr, BT, DM, DM);
    gemm_split<0,0><<<dim3(32,8),256,0,stream>>>(hshi, hslo, w1hi, w1lo, enc_bk+bo_,
        t1, (short*)nullptr, (short*)nullptr, BT, DM, DM);
    gemm_split<0,0><<<dim3(32,8),256,0,stream>>>(hshi, hslo, w2hi, w2lo, enc_bv+bo_,
        t2, (short*)nullptr, (short*)nullptr, BT, DM, DM);
    attn_enc<<<dim3(TT/256, BB*NH),256,0,stream>>>(t0, t1, t2, t3hi, t3lo);
    gemm_split<0,2><<<dim3(32,8),256,0,stream>>>(t3hi, t3lo, w3hi, w3lo, enc_bo+bo_,
        hn, hnhi, hnlo, BT, DM, DM);
    cvt(ffe_W1, wfhi, wflo, (size_t)DFFN*DM);
    gemm_split<1,1><<<dim3(32,32),256,0,stream>>>(hnhi, hnlo, wfhi, wflo, ffe_b1,
        (float*)nullptr, fmhi, fmlo, BT, DFFN, DM);
    cvt(ffe_W2, wfhi, wflo, (size_t)DM*DFFN);
    gemm_split<0,0><<<dim3(32,8),256,0,stream>>>(fmhi, fmlo, wfhi, wflo, ffe_b2,
        t4, (short*)nullptr, (short*)nullptr, BT, DM, DFFN);
    ln_add_split<<<BT,256,0,stream>>>(hn, t4, ne_g, ne_b, hshi, hslo);
  }

  // ---- cross-attention K/V cache (bf16; h fixed after encoder, weights shared) ----
  for (int l=0; l<NL; ++l) {
    const size_t wo = (size_t)l*DM*DM, bo_ = (size_t)l*DM;
    cvt(dec_Wk+wo, w0hi, w0lo, MM);
    cvt(dec_Wv+wo, w1hi, w1lo, MM);
    gemm_split<0,3><<<dim3(32,8),256,0,stream>>>(hshi, hslo, w0hi, w0lo, dec_bk+bo_,
        (float*)nullptr, kcb+(size_t)l*BT*DM, (short*)nullptr, BT, DM, DM);
    gemm_split<0,3><<<dim3(32,8),256,0,stream>>>(hshi, hslo, w1hi, w1lo, dec_bv+bo_,
        (float*)nullptr, vcb+(size_t)l*BT*DM, (short*)nullptr, BT, DM, DM);
  }

  // ---- decoder split weights (once; into dead encoder buffers) ----
  for (int l=0; l<NL; ++l) {
    const size_t wo = (size_t)l*DM*DM;
    cvt(dec_Wq+wo, dwq + (size_t)l*2*MM, dwq + (size_t)l*2*MM + MM, MM);
    cvt(dec_Wk+wo, dwk + (size_t)l*2*MM, dwk + (size_t)l*2*MM + MM, MM);
    cvt(dec_Wv+wo, dwv + (size_t)l*2*MM, dwv + (size_t)l*2*MM + MM, MM);
    cvt(dec_Wo+wo, dwo + (size_t)l*2*MM, dwo + (size_t)l*2*MM + MM, MM);
  }
  cvt(ffd_W1, fw1h, fw1l, (size_t)DFFN*DM);
  cvt(ffd_W2, fw2h, fw2l, (size_t)DM*DFFN);

  #define GD(MRv, grid, ...) do { switch(MRv){ \
    case 1: gemm_dec<1><<<grid,256,0,stream>>>(__VA_ARGS__); break; \
    case 2: gemm_dec<2><<<grid,256,0,stream>>>(__VA_ARGS__); break; \
    case 3: gemm_dec<3><<<grid,256,0,stream>>>(__VA_ARGS__); break; \
    case 4: gemm_dec<4><<<grid,256,0,stream>>>(__VA_ARGS__); break; \
    case 5: gemm_dec<5><<<grid,256,0,stream>>>(__VA_ARGS__); break; \
    default: gemm_dec<6><<<grid,256,0,stream>>>(__VA_ARGS__); break; } } while(0)

  // ---- decoder (split-bf16 MFMA, packed variable-M) ----
  for (int s=0; s<NSTEP; ++s) {
    const int n = s+1;
    const int rows = 4*n;
    const int Mt = (rows + 15) & ~15;
    const int MR = Mt >> 4;
    dec_prep_split<<<rows,256,0,stream>>>(dbhi, dblo, tok);
    for (int l=0; l<NL; ++l) {
      const size_t bo_ = (size_t)l*DM;
      short* qh = dwq + (size_t)l*2*MM; short* ql = qh + MM;
      short* kh = dwk + (size_t)l*2*MM; short* kl = kh + MM;
      short* vh = dwv + (size_t)l*2*MM; short* vl = vh + MM;
      short* oh = dwo + (size_t)l*2*MM; short* ol = oh + MM;
      // self-attn QKV
      GD(MR, dim3(8,8,3), dbhi,dblo, qh,ql, kh,kl, vh,vl, part, DM, DM, 8);
      reduce_dec<0,0><<<dim3(Mt*4,3),256,0,stream>>>(part, dec_bq+bo_, dec_bk+bo_, dec_bv+bo_,
          dq, dk, dv_, (short*)nullptr, (short*)nullptr, DM, 8);
      attn_dec_selfp<<<BB*NH,256,0,stream>>>(dq, dk, dv_, dahi, dalo, n);
      // self O
      GD(MR, dim3(8,8,1), dahi,dalo, oh,ol, oh,ol, oh,ol, part, DM, DM, 8);
      reduce_dec<0,1><<<dim3(Mt*4,1),256,0,stream>>>(part, dec_bo+bo_, dec_bo+bo_, dec_bo+bo_,
          (float*)nullptr,(float*)nullptr,(float*)nullptr, dbhi, dblo, DM, 8);
      // cross Q
      GD(MR, dim3(8,8,1), dbhi,dblo, qh,ql, qh,ql, qh,ql, part, DM, DM, 8);
      reduce_dec<0,0><<<dim3(Mt*4,1),256,0,stream>>>(part, dec_bq+bo_, dec_bq+bo_, dec_bq+bo_,
          dq, dq, dq, (short*)nullptr, (short*)nullptr, DM, 8);
      attn_cross_part<<<dim3(CSPLIT, BB*NH),256,0,stream>>>(dq, kcb+(size_t)l*BT*DM,
          vcb+(size_t)l*BT*DM, opart, mlp, n);
      attn_cross_comb<<<dim3(BB*NH, 6),256,0,stream>>>(opart, mlp, dahi, dalo, n);
      // cross O
      GD(MR, dim3(8,8,1), dahi,dalo, oh,ol, oh,ol, oh,ol, part, DM, DM, 8);
      reduce_dec<0,2><<<dim3(Mt*4,1),256,0,stream>>>(part, dec_bo+bo_, dec_bo+bo_, dec_bo+bo_,
          dbuf, dbuf, dbuf, dbhi, dblo, DM, 8);
      // FFN
      GD(MR, dim3(32,8,1), dbhi,dblo, fw1h,fw1l, fw1h,fw1l, fw1h,fw1l, part, DFFN, DM, 8);
      reduce_dec<1,1><<<dim3(Mt*16,1),256,0,stream>>>(part, ffd_b1, ffd_b1, ffd_b1,
          (float*)nullptr,(float*)nullptr,(float*)nullptr, dmhi, dmlo, DFFN, 8);
      GD(MR, dim3(8,16,1), dmhi,dmlo, fw2h,fw2l, fw2h,fw2l, fw2h,fw2l, part, DM, DFFN, 16);
      reduce_dec<0,0><<<dim3(Mt*4,1),256,0,stream>>>(part, ffd_b2, ffd_b2, ffd_b2,
          dffo, dffo, dffo, (short*)nullptr, (short*)nullptr, DM, 16);
      ln_add_dec<<<rows,256,0,stream>>>(dbuf, dffo, nd_g, nd_b, dbuf, dbhi, dblo);
    }
    out_step<<<BB,256,0,stream>>>(dbuf, out_W, out_b, temb_W, temb_b, dout, tok, s);
  }
  #undef GD
}